// Round 4
// baseline (579.190 us; speedup 1.0000x reference)
//
#include <hip/hip_runtime.h>

// ---------------------------------------------------------------------------
// GIN (2 GINConv layers + linear head) on MI355X.
// Round 4: MLP GEMMs on matrix cores via split-bf16 (hi/lo) MFMA 16x16x32.
//   - prep kernel: W -> W^T as bf16 hi/lo (B-fragments read from global, L2-hot)
//   - A tiles in LDS, k-plane-major packed (hi,lo) dwords, stride 66 (bank-safe)
//   - per-stage: 4 waves x (1 m-tile x 8 n-tiles), 3 MFMA per tile-kchunk
//   - inter-stage: C-layout -> A-frag-layout via LDS ping-pong (m120 pattern)
// CSR build + agg kernels unchanged from round 2/3.
// ---------------------------------------------------------------------------

typedef __attribute__((ext_vector_type(8))) short short8;
typedef __attribute__((ext_vector_type(4))) float f32x4;
union F8 { unsigned u[4]; short8 s; };

// pack float -> (lo bf16 << 16) | hi bf16, both RNE
__device__ inline unsigned bfpair(float v) {
    unsigned u = __float_as_uint(v);
    unsigned rh = u + 0x7fffu + ((u >> 16) & 1u);
    unsigned hf = rh & 0xffff0000u;              // hi rounded, as f32 bits
    float lof = v - __uint_as_float(hf);
    unsigned ul = __float_as_uint(lof);
    unsigned rl = ul + 0x7fffu + ((ul >> 16) & 1u);
    return (rh >> 16) | (rl & 0xffff0000u);
}

// ---------------- CSR build (unchanged) ----------------

constexpr int BUCKET_SHIFT = 9;
constexpr int BUCKET_NODES = 1 << BUCKET_SHIFT;
constexpr int CAP = 10240;
constexpr int EPB = 4096;
constexpr int NBUCK_MAX = 256;

__global__ __launch_bounds__(256) void init_gcur_kernel(int* __restrict__ gcur, int nbuck) {
    int i = threadIdx.x;
    if (i < nbuck) gcur[i] = i * CAP;
}

__global__ __launch_bounds__(256) void bucket_scatter_kernel(const int* __restrict__ ei, int E,
                                                             int* __restrict__ gcur,
                                                             int* __restrict__ gsrc,
                                                             int* __restrict__ gdst,
                                                             int nbuck) {
    __shared__ int ssrc[EPB];
    __shared__ int sdst[EPB];
    __shared__ int lcnt[NBUCK_MAX];
    __shared__ int lbase[NBUCK_MAX];
    __shared__ int lcur[NBUCK_MAX];
    __shared__ int gbase[NBUCK_MAX];
    __shared__ int stmp[256];

    const int t = threadIdx.x;
    const int e0 = blockIdx.x * EPB;
    const int ecnt = min(EPB, E - e0);

    for (int i = t; i < NBUCK_MAX; i += 256) lcnt[i] = 0;
    __syncthreads();

    for (int i = t; i < ecnt; i += 256) {
        int d = ei[E + e0 + i];
        atomicAdd(&lcnt[d >> BUCKET_SHIFT], 1);
    }
    __syncthreads();

    int v = lcnt[t];
    stmp[t] = v;
    __syncthreads();
    #pragma unroll
    for (int off = 1; off < 256; off <<= 1) {
        int add = (t >= off) ? stmp[t - off] : 0;
        __syncthreads();
        stmp[t] += add;
        __syncthreads();
    }
    lbase[t] = stmp[t] - v;
    lcur[t] = stmp[t] - v;
    __syncthreads();

    for (int i = t; i < ecnt; i += 256) {
        int s = ei[e0 + i];
        int d = ei[E + e0 + i];
        int p = atomicAdd(&lcur[d >> BUCKET_SHIFT], 1);
        ssrc[p] = s;
        sdst[p] = d;
    }
    __syncthreads();

    if (t < nbuck) {
        int c = lcnt[t];
        gbase[t] = (c > 0) ? atomicAdd(&gcur[t], c) : 0;
    }
    __syncthreads();

    for (int i = t; i < ecnt; i += 256) {
        int d = sdst[i];
        int b = d >> BUCKET_SHIFT;
        int gp = gbase[b] + (i - lbase[b]);
        if (gp < (b + 1) * CAP) {
            gsrc[gp] = ssrc[i];
            gdst[gp] = d;
        }
    }
}

__global__ __launch_bounds__(256) void bucket_hist_kernel(const int* __restrict__ gdst,
                                                          const int* __restrict__ gcur,
                                                          int* __restrict__ cnt, int N) {
    __shared__ int h[BUCKET_NODES];
    const int t = threadIdx.x;
    const int b = blockIdx.x;
    const int base = b << BUCKET_SHIFT;
    for (int i = t; i < BUCKET_NODES; i += 256) h[i] = 0;
    __syncthreads();
    int cb = min(gcur[b] - b * CAP, CAP);
    const int* dd = gdst + (size_t)b * CAP;
    for (int i = t; i < cb; i += 256) atomicAdd(&h[dd[i] - base], 1);
    __syncthreads();
    for (int i = t; i < BUCKET_NODES && base + i < N; i += 256) cnt[base + i] = h[i];
}

__global__ __launch_bounds__(256) void scan_block_kernel(const int* __restrict__ cnt,
                                                         int* __restrict__ rs,
                                                         int* __restrict__ partials,
                                                         int N) {
    __shared__ int s[256];
    int t = threadIdx.x;
    int i = blockIdx.x * 256 + t;
    int v = (i < N) ? cnt[i] : 0;
    s[t] = v;
    __syncthreads();
    #pragma unroll
    for (int off = 1; off < 256; off <<= 1) {
        int add = (t >= off) ? s[t - off] : 0;
        __syncthreads();
        s[t] += add;
        __syncthreads();
    }
    if (i < N) rs[i] = s[t] - v;
    if (t == 255) partials[blockIdx.x] = s[255];
}

__global__ __launch_bounds__(512) void scan_partials_kernel(int* __restrict__ partials,
                                                            int nb) {
    __shared__ int s[512];
    int t = threadIdx.x;
    int v = (t < nb) ? partials[t] : 0;
    s[t] = v;
    __syncthreads();
    #pragma unroll
    for (int off = 1; off < 512; off <<= 1) {
        int add = (t >= off) ? s[t - off] : 0;
        __syncthreads();
        s[t] += add;
        __syncthreads();
    }
    if (t < nb) partials[t] = s[t] - v;
}

__global__ __launch_bounds__(256) void scan_add_kernel(int* __restrict__ rs,
                                                       const int* __restrict__ partials,
                                                       int N, int E) {
    int i = blockIdx.x * 256 + threadIdx.x;
    if (i < N) rs[i] += partials[blockIdx.x];
    if (i == 0) rs[N] = E;
}

__global__ __launch_bounds__(256) void bucket_fill_kernel(const int* __restrict__ gsrc,
                                                          const int* __restrict__ gdst,
                                                          const int* __restrict__ gcur,
                                                          const int* __restrict__ rs,
                                                          int* __restrict__ edge_src, int N) {
    __shared__ int cur[BUCKET_NODES];
    const int t = threadIdx.x;
    const int b = blockIdx.x;
    const int base = b << BUCKET_SHIFT;
    for (int i = t; i < BUCKET_NODES; i += 256) cur[i] = rs[min(base + i, N)];
    __syncthreads();
    int cb = min(gcur[b] - b * CAP, CAP);
    const int* ss = gsrc + (size_t)b * CAP;
    const int* dd = gdst + (size_t)b * CAP;
    for (int i = t; i < cb; i += 256) {
        int d = dd[i];
        int s = ss[i];
        int p = atomicAdd(&cur[d - base], 1);
        edge_src[p] = s;
    }
}

// ---------------- aggregation (unchanged) ----------------

template <int D>
__global__ __launch_bounds__(256) void agg_kernel(const float* __restrict__ H,
                                                  const int* __restrict__ row_start,
                                                  const int* __restrict__ edge_src,
                                                  float* __restrict__ Z, int N) {
    int wave = threadIdx.x >> 6;
    int lane = threadIdx.x & 63;
    int node = blockIdx.x * 4 + wave;
    if (node >= N) return;
    int beg = row_start[node];
    int end = row_start[node + 1];
    const size_t base = (size_t)node * D;
    float acc0 = H[base + lane];
    float acc1 = 0.f;
    if constexpr (D == 128) acc1 = H[base + 64 + lane];
    int i = beg;
    for (; i + 4 <= end; i += 4) {
        int s0 = edge_src[i + 0];
        int s1 = edge_src[i + 1];
        int s2 = edge_src[i + 2];
        int s3 = edge_src[i + 3];
        float a = H[(size_t)s0 * D + lane] + H[(size_t)s1 * D + lane] +
                  H[(size_t)s2 * D + lane] + H[(size_t)s3 * D + lane];
        acc0 += a;
        if constexpr (D == 128) {
            float b = H[(size_t)s0 * D + 64 + lane] + H[(size_t)s1 * D + 64 + lane] +
                      H[(size_t)s2 * D + 64 + lane] + H[(size_t)s3 * D + 64 + lane];
            acc1 += b;
        }
    }
    for (; i < end; ++i) {
        int s = edge_src[i];
        acc0 += H[(size_t)s * D + lane];
        if constexpr (D == 128) acc1 += H[(size_t)s * D + 64 + lane];
    }
    Z[base + lane] = acc0;
    if constexpr (D == 128) Z[base + 64 + lane] = acc1;
}

// ---------------- weight prep: W[K][N] fp32 -> Wt[N][K] bf16 hi/lo ----------
// flat element ranges: W1a[64x128]@0, W1b[128x128]@8192, W2a@24576,
// W2b@40960, Wlin[128x64]@57344; total 65536.

__global__ __launch_bounds__(256) void prep_weights_kernel(const float* __restrict__ W1a,
                                                           const float* __restrict__ W1b,
                                                           const float* __restrict__ W2a,
                                                           const float* __restrict__ W2b,
                                                           const float* __restrict__ Wlin,
                                                           short* __restrict__ hi,
                                                           short* __restrict__ lo) {
    int i = blockIdx.x * 256 + threadIdx.x;   // 0..65535
    const float* W;
    int base, K, N;
    if (i < 8192)       { W = W1a;  base = 0;     K = 64;  N = 128; }
    else if (i < 24576) { W = W1b;  base = 8192;  K = 128; N = 128; }
    else if (i < 40960) { W = W2a;  base = 24576; K = 128; N = 128; }
    else if (i < 57344) { W = W2b;  base = 40960; K = 128; N = 128; }
    else                { W = Wlin; base = 57344; K = 128; N = 64;  }
    int rel = i - base;
    int n = rel / K;
    int k = rel - n * K;
    float v = W[k * N + n];
    unsigned p = bfpair(v);
    hi[i] = (short)(p & 0xffffu);
    lo[i] = (short)(p >> 16);
}

// ---------------- MFMA fused MLP --------------------------------------------
// LDS A-tile layout ("k-plane-major packed"): for m-tile T (0..3), k-chunk c,
// k-index j (0..7), lane l: dword at ((T*KC + c)*8 + j)*66 + l holds
// (lo<<16)|hi of A[T*16 + (l&15)][c*32 + (l>>4)*8 + j].  Stride 66 keeps all
// access patterns <=4-way on the 32 banks.

template <int K>
__device__ inline void stage_global(const float* __restrict__ z, int M, int m0,
                                    unsigned* __restrict__ P, int t) {
    constexpr int KC = K / 32;
    constexpr int NF = 4 * KC * 64;
    #pragma unroll
    for (int fi = t; fi < NF; fi += 256) {
        int l = fi & 63;
        int tc = fi >> 6;
        int c = tc & (KC - 1);
        int T = tc / KC;
        int row = m0 + T * 16 + (l & 15);
        if (row >= M) row = M - 1;
        int kb = c * 32 + ((l >> 4) << 3);
        const float* p = z + (size_t)row * K + kb;
        float4 v0 = *reinterpret_cast<const float4*>(p);
        float4 v1 = *reinterpret_cast<const float4*>(p + 4);
        int base = ((T * KC + c) * 8) * 66 + l;
        P[base + 0 * 66] = bfpair(v0.x);
        P[base + 1 * 66] = bfpair(v0.y);
        P[base + 2 * 66] = bfpair(v0.z);
        P[base + 3 * 66] = bfpair(v0.w);
        P[base + 4 * 66] = bfpair(v1.x);
        P[base + 5 * 66] = bfpair(v1.y);
        P[base + 6 * 66] = bfpair(v1.z);
        P[base + 7 * 66] = bfpair(v1.w);
    }
}

template <int K, int NT>
__device__ inline void stage_compute(const unsigned* __restrict__ P,
                                     const short* __restrict__ WH,
                                     const short* __restrict__ WL,
                                     int w, int lane, f32x4* acc) {
    constexpr int KC = K / 32;
    const int q8 = (lane >> 4) << 3;
    const int ln = lane & 15;
    for (int c = 0; c < KC; ++c) {
        unsigned d[8];
        int base = ((w * KC + c) * 8) * 66 + lane;
        #pragma unroll
        for (int j = 0; j < 8; ++j) d[j] = P[base + j * 66];
        F8 ah, al;
        #pragma unroll
        for (int j = 0; j < 4; ++j) {
            ah.u[j] = __builtin_amdgcn_perm(d[2 * j + 1], d[2 * j], 0x05040100u);
            al.u[j] = __builtin_amdgcn_perm(d[2 * j + 1], d[2 * j], 0x07060302u);
        }
        const short* bhp = WH + (size_t)ln * K + c * 32 + q8;
        const short* blp = WL + (size_t)ln * K + c * 32 + q8;
        #pragma unroll
        for (int nt = 0; nt < NT; ++nt) {
            F8 bh, bl;
            bh.s = *reinterpret_cast<const short8*>(bhp + (size_t)nt * 16 * K);
            bl.s = *reinterpret_cast<const short8*>(blp + (size_t)nt * 16 * K);
            acc[nt] = __builtin_amdgcn_mfma_f32_16x16x32_bf16(ah.s, bh.s, acc[nt], 0, 0, 0);
            acc[nt] = __builtin_amdgcn_mfma_f32_16x16x32_bf16(al.s, bh.s, acc[nt], 0, 0, 0);
            acc[nt] = __builtin_amdgcn_mfma_f32_16x16x32_bf16(ah.s, bl.s, acc[nt], 0, 0, 0);
        }
    }
}

// bias + relu + C-layout -> next-stage A-frag layout (KC=4), into Pout
__device__ inline void epilogue_lds(const f32x4* acc, const float* __restrict__ bias,
                                    unsigned* __restrict__ Pout, int w, int lane) {
    int q = lane >> 4, ln = lane & 15;
    #pragma unroll
    for (int nt = 0; nt < 8; ++nt) {
        int col = nt * 16 + ln;
        float b = bias[col];
        int c = col >> 5, jj = col & 7, q2 = (col >> 3) & 3;
        int pb = ((w * 4 + c) * 8 + jj) * 66;
        #pragma unroll
        for (int r = 0; r < 4; ++r) {
            float v = fmaxf(acc[nt][r] + b, 0.f);
            Pout[pb + ((q * 4 + r) | (q2 << 4))] = bfpair(v);
        }
    }
}

// conv1 MLP: z[M,64] -> relu(relu(z@Wa+ba)@Wb+bb) = h1[M,128]
__global__ __launch_bounds__(256) void mfma_mlp_A(const float* __restrict__ z,
                                                  const short* __restrict__ WaH,
                                                  const short* __restrict__ WaL,
                                                  const float* __restrict__ ba,
                                                  const short* __restrict__ WbH,
                                                  const short* __restrict__ WbL,
                                                  const float* __restrict__ bb,
                                                  float* __restrict__ Hout, int M) {
    __shared__ unsigned P0[4 * 4 * 8 * 66];
    __shared__ unsigned P1[4 * 4 * 8 * 66];
    const int t = threadIdx.x;
    const int w = t >> 6, lane = t & 63;
    const int m0 = blockIdx.x * 64;
    const int q = lane >> 4, ln = lane & 15;

    stage_global<64>(z, M, m0, P0, t);
    __syncthreads();

    f32x4 acc[8];
    #pragma unroll
    for (int i = 0; i < 8; ++i) acc[i] = (f32x4){0.f, 0.f, 0.f, 0.f};
    stage_compute<64, 8>(P0, WaH, WaL, w, lane, acc);
    epilogue_lds(acc, ba, P1, w, lane);
    __syncthreads();

    #pragma unroll
    for (int i = 0; i < 8; ++i) acc[i] = (f32x4){0.f, 0.f, 0.f, 0.f};
    stage_compute<128, 8>(P1, WbH, WbL, w, lane, acc);

    #pragma unroll
    for (int nt = 0; nt < 8; ++nt) {
        int col = nt * 16 + ln;
        float b = bb[col];
        #pragma unroll
        for (int r = 0; r < 4; ++r) {
            int row = m0 + w * 16 + q * 4 + r;
            if (row < M) Hout[(size_t)row * 128 + col] = fmaxf(acc[nt][r] + b, 0.f);
        }
    }
}

// conv2 MLP + head: z[M,128] -> (relu(relu(z@Wa+ba)@Wb+bb))@Wl+bl = out[M,64]
__global__ __launch_bounds__(256) void mfma_mlp_B(const float* __restrict__ z,
                                                  const short* __restrict__ WaH,
                                                  const short* __restrict__ WaL,
                                                  const float* __restrict__ ba,
                                                  const short* __restrict__ WbH,
                                                  const short* __restrict__ WbL,
                                                  const float* __restrict__ bb,
                                                  const short* __restrict__ WlH,
                                                  const short* __restrict__ WlL,
                                                  const float* __restrict__ bl,
                                                  float* __restrict__ Out, int M) {
    __shared__ unsigned P0[4 * 4 * 8 * 66];
    __shared__ unsigned P1[4 * 4 * 8 * 66];
    const int t = threadIdx.x;
    const int w = t >> 6, lane = t & 63;
    const int m0 = blockIdx.x * 64;
    const int q = lane >> 4, ln = lane & 15;

    stage_global<128>(z, M, m0, P0, t);
    __syncthreads();

    f32x4 acc[8];
    #pragma unroll
    for (int i = 0; i < 8; ++i) acc[i] = (f32x4){0.f, 0.f, 0.f, 0.f};
    stage_compute<128, 8>(P0, WaH, WaL, w, lane, acc);
    epilogue_lds(acc, ba, P1, w, lane);
    __syncthreads();

    #pragma unroll
    for (int i = 0; i < 8; ++i) acc[i] = (f32x4){0.f, 0.f, 0.f, 0.f};
    stage_compute<128, 8>(P1, WbH, WbL, w, lane, acc);
    epilogue_lds(acc, bb, P0, w, lane);
    __syncthreads();

    f32x4 accC[4];
    #pragma unroll
    for (int i = 0; i < 4; ++i) accC[i] = (f32x4){0.f, 0.f, 0.f, 0.f};
    stage_compute<128, 4>(P0, WlH, WlL, w, lane, accC);

    #pragma unroll
    for (int nt = 0; nt < 4; ++nt) {
        int col = nt * 16 + ln;
        float b = bl[col];
        #pragma unroll
        for (int r = 0; r < 4; ++r) {
            int row = m0 + w * 16 + q * 4 + r;
            if (row < M) Out[(size_t)row * 64 + col] = accC[nt][r] + b;
        }
    }
}

// ---------------------------------------------------------------------------

extern "C" void kernel_launch(void* const* d_in, const int* in_sizes, int n_in,
                              void* d_out, int out_size, void* d_ws, size_t ws_size,
                              hipStream_t stream) {
    const float* x    = (const float*)d_in[0];
    const int*   ei   = (const int*)d_in[1];
    const float* W1a  = (const float*)d_in[2];
    const float* b1a  = (const float*)d_in[3];
    const float* W1b  = (const float*)d_in[4];
    const float* b1b  = (const float*)d_in[5];
    const float* W2a  = (const float*)d_in[6];
    const float* b2a  = (const float*)d_in[7];
    const float* W2b  = (const float*)d_in[8];
    const float* b2b  = (const float*)d_in[9];
    const float* Wlin = (const float*)d_in[10];
    const float* blin = (const float*)d_in[11];
    float* out = (float*)d_out;

    const int N = in_sizes[0] / 64;   // 100000
    const int E = in_sizes[1] / 2;    // 1600000
    const int NBUCK = (N + BUCKET_NODES - 1) >> BUCKET_SHIFT;  // 196

    // workspace layout
    char* ws = (char*)d_ws;
    const size_t bufBytes = (size_t)N * 128 * sizeof(float);  // 51.2 MB
    float* A  = (float*)(ws + 0);
    float* B  = (float*)(ws + bufBytes);
    float* Cb = (float*)(ws + 2 * bufBytes);
    size_t off = 3 * bufBytes;
    int* row_start = (int*)(ws + off); off += ((size_t)(N + 1) * 4 + 15) & ~(size_t)15;
    int* cnt       = (int*)(ws + off); off += ((size_t)N * 4 + 15) & ~(size_t)15;
    int* partials  = (int*)(ws + off); off += 4096;
    int* gcur      = (int*)(ws + off); off += 4096;
    int* edge_src  = (int*)(ws + off); off += (size_t)E * 4;
    // CSR scratch aliases B[0 .. 16MB); bf16 weights alias B[32MB ..): disjoint.
    int* gsrc = (int*)B;
    int* gdst = (int*)B + (size_t)NBUCK * CAP;
    short* wHi = (short*)((char*)B + (32u << 20));
    short* wLo = wHi + 65536;
    // per-matrix transposed offsets
    short* w1aH = wHi + 0;     short* w1aL = wLo + 0;
    short* w1bH = wHi + 8192;  short* w1bL = wLo + 8192;
    short* w2aH = wHi + 24576; short* w2aL = wLo + 24576;
    short* w2bH = wHi + 40960; short* w2bL = wLo + 40960;
    short* wlH  = wHi + 57344; short* wlL  = wLo + 57344;

    const int NB_N = (N + 255) / 256;          // 391
    const int NB_A = (N + 3) / 4;              // 25000 agg blocks
    const int NB_G = (N + 63) / 64;            // 1563 MLP blocks
    const int NB_S = (E + EPB - 1) / EPB;      // 391 scatter blocks

    // 0. weight prep (independent of CSR chain)
    prep_weights_kernel<<<256, 256, 0, stream>>>(W1a, W1b, W2a, W2b, Wlin, wHi, wLo);

    // 1. CSR build, bucket-binned
    init_gcur_kernel<<<1, 256, 0, stream>>>(gcur, NBUCK);
    bucket_scatter_kernel<<<NB_S, 256, 0, stream>>>(ei, E, gcur, gsrc, gdst, NBUCK);
    bucket_hist_kernel<<<NBUCK, 256, 0, stream>>>(gdst, gcur, cnt, N);
    scan_block_kernel<<<NB_N, 256, 0, stream>>>(cnt, row_start, partials, N);
    scan_partials_kernel<<<1, 512, 0, stream>>>(partials, NB_N);
    scan_add_kernel<<<NB_N, 256, 0, stream>>>(row_start, partials, N, E);
    bucket_fill_kernel<<<NBUCK, 256, 0, stream>>>(gsrc, gdst, gcur, row_start, edge_src, N);

    // 2. conv1: agg + MFMA MLP
    agg_kernel<64><<<NB_A, 256, 0, stream>>>(x, row_start, edge_src, A, N);
    mfma_mlp_A<<<NB_G, 256, 0, stream>>>(A, w1aH, w1aL, b1a, w1bH, w1bL, b1b, Cb, N);

    // 3. conv2 + head: agg + MFMA MLP(+head)
    agg_kernel<128><<<NB_A, 256, 0, stream>>>(Cb, row_start, edge_src, A, N);
    mfma_mlp_B<<<NB_G, 256, 0, stream>>>(A, w2aH, w2aL, b2a, w2bH, w2bL, b2b,
                                         wlH, wlL, blin, out, N);
}

// Round 5
// 564.706 us; speedup vs baseline: 1.0256x; 1.0256x over previous
//
#include <hip/hip_runtime.h>

// ---------------------------------------------------------------------------
// GIN (2 GINConv layers + linear head) on MI355X.
// Round 5: fix latency-bound MFMA MLPs.
//   - single LDS P buffer (33.8 KB -> up to 4 blocks/CU), extra barrier
//     between stage-compute reads and epilogue writes
//   - software-pipelined B-fragment prefetch (groups of 4 n-tiles, 2-deep
//     register double buffer) so L2 latency overlaps MFMA
//   - __launch_bounds__(256,2): 256-VGPR budget, no spills
// CSR build + agg kernels unchanged.
// ---------------------------------------------------------------------------

typedef __attribute__((ext_vector_type(8))) short short8;
typedef __attribute__((ext_vector_type(4))) float f32x4;
union F8 { unsigned u[4]; short8 s; };

// pack float -> (lo bf16 << 16) | hi bf16, both RNE
__device__ inline unsigned bfpair(float v) {
    unsigned u = __float_as_uint(v);
    unsigned rh = u + 0x7fffu + ((u >> 16) & 1u);
    unsigned hf = rh & 0xffff0000u;              // hi rounded, as f32 bits
    float lof = v - __uint_as_float(hf);
    unsigned ul = __float_as_uint(lof);
    unsigned rl = ul + 0x7fffu + ((ul >> 16) & 1u);
    return (rh >> 16) | (rl & 0xffff0000u);
}

// ---------------- CSR build (unchanged) ----------------

constexpr int BUCKET_SHIFT = 9;
constexpr int BUCKET_NODES = 1 << BUCKET_SHIFT;
constexpr int CAP = 10240;
constexpr int EPB = 4096;
constexpr int NBUCK_MAX = 256;

__global__ __launch_bounds__(256) void init_gcur_kernel(int* __restrict__ gcur, int nbuck) {
    int i = threadIdx.x;
    if (i < nbuck) gcur[i] = i * CAP;
}

__global__ __launch_bounds__(256) void bucket_scatter_kernel(const int* __restrict__ ei, int E,
                                                             int* __restrict__ gcur,
                                                             int* __restrict__ gsrc,
                                                             int* __restrict__ gdst,
                                                             int nbuck) {
    __shared__ int ssrc[EPB];
    __shared__ int sdst[EPB];
    __shared__ int lcnt[NBUCK_MAX];
    __shared__ int lbase[NBUCK_MAX];
    __shared__ int lcur[NBUCK_MAX];
    __shared__ int gbase[NBUCK_MAX];
    __shared__ int stmp[256];

    const int t = threadIdx.x;
    const int e0 = blockIdx.x * EPB;
    const int ecnt = min(EPB, E - e0);

    for (int i = t; i < NBUCK_MAX; i += 256) lcnt[i] = 0;
    __syncthreads();

    for (int i = t; i < ecnt; i += 256) {
        int d = ei[E + e0 + i];
        atomicAdd(&lcnt[d >> BUCKET_SHIFT], 1);
    }
    __syncthreads();

    int v = lcnt[t];
    stmp[t] = v;
    __syncthreads();
    #pragma unroll
    for (int off = 1; off < 256; off <<= 1) {
        int add = (t >= off) ? stmp[t - off] : 0;
        __syncthreads();
        stmp[t] += add;
        __syncthreads();
    }
    lbase[t] = stmp[t] - v;
    lcur[t] = stmp[t] - v;
    __syncthreads();

    for (int i = t; i < ecnt; i += 256) {
        int s = ei[e0 + i];
        int d = ei[E + e0 + i];
        int p = atomicAdd(&lcur[d >> BUCKET_SHIFT], 1);
        ssrc[p] = s;
        sdst[p] = d;
    }
    __syncthreads();

    if (t < nbuck) {
        int c = lcnt[t];
        gbase[t] = (c > 0) ? atomicAdd(&gcur[t], c) : 0;
    }
    __syncthreads();

    for (int i = t; i < ecnt; i += 256) {
        int d = sdst[i];
        int b = d >> BUCKET_SHIFT;
        int gp = gbase[b] + (i - lbase[b]);
        if (gp < (b + 1) * CAP) {
            gsrc[gp] = ssrc[i];
            gdst[gp] = d;
        }
    }
}

__global__ __launch_bounds__(256) void bucket_hist_kernel(const int* __restrict__ gdst,
                                                          const int* __restrict__ gcur,
                                                          int* __restrict__ cnt, int N) {
    __shared__ int h[BUCKET_NODES];
    const int t = threadIdx.x;
    const int b = blockIdx.x;
    const int base = b << BUCKET_SHIFT;
    for (int i = t; i < BUCKET_NODES; i += 256) h[i] = 0;
    __syncthreads();
    int cb = min(gcur[b] - b * CAP, CAP);
    const int* dd = gdst + (size_t)b * CAP;
    for (int i = t; i < cb; i += 256) atomicAdd(&h[dd[i] - base], 1);
    __syncthreads();
    for (int i = t; i < BUCKET_NODES && base + i < N; i += 256) cnt[base + i] = h[i];
}

__global__ __launch_bounds__(256) void scan_block_kernel(const int* __restrict__ cnt,
                                                         int* __restrict__ rs,
                                                         int* __restrict__ partials,
                                                         int N) {
    __shared__ int s[256];
    int t = threadIdx.x;
    int i = blockIdx.x * 256 + t;
    int v = (i < N) ? cnt[i] : 0;
    s[t] = v;
    __syncthreads();
    #pragma unroll
    for (int off = 1; off < 256; off <<= 1) {
        int add = (t >= off) ? s[t - off] : 0;
        __syncthreads();
        s[t] += add;
        __syncthreads();
    }
    if (i < N) rs[i] = s[t] - v;
    if (t == 255) partials[blockIdx.x] = s[255];
}

__global__ __launch_bounds__(512) void scan_partials_kernel(int* __restrict__ partials,
                                                            int nb) {
    __shared__ int s[512];
    int t = threadIdx.x;
    int v = (t < nb) ? partials[t] : 0;
    s[t] = v;
    __syncthreads();
    #pragma unroll
    for (int off = 1; off < 512; off <<= 1) {
        int add = (t >= off) ? s[t - off] : 0;
        __syncthreads();
        s[t] += add;
        __syncthreads();
    }
    if (t < nb) partials[t] = s[t] - v;
}

__global__ __launch_bounds__(256) void scan_add_kernel(int* __restrict__ rs,
                                                       const int* __restrict__ partials,
                                                       int N, int E) {
    int i = blockIdx.x * 256 + threadIdx.x;
    if (i < N) rs[i] += partials[blockIdx.x];
    if (i == 0) rs[N] = E;
}

__global__ __launch_bounds__(256) void bucket_fill_kernel(const int* __restrict__ gsrc,
                                                          const int* __restrict__ gdst,
                                                          const int* __restrict__ gcur,
                                                          const int* __restrict__ rs,
                                                          int* __restrict__ edge_src, int N) {
    __shared__ int cur[BUCKET_NODES];
    const int t = threadIdx.x;
    const int b = blockIdx.x;
    const int base = b << BUCKET_SHIFT;
    for (int i = t; i < BUCKET_NODES; i += 256) cur[i] = rs[min(base + i, N)];
    __syncthreads();
    int cb = min(gcur[b] - b * CAP, CAP);
    const int* ss = gsrc + (size_t)b * CAP;
    const int* dd = gdst + (size_t)b * CAP;
    for (int i = t; i < cb; i += 256) {
        int d = dd[i];
        int s = ss[i];
        int p = atomicAdd(&cur[d - base], 1);
        edge_src[p] = s;
    }
}

// ---------------- aggregation (unchanged) ----------------

template <int D>
__global__ __launch_bounds__(256) void agg_kernel(const float* __restrict__ H,
                                                  const int* __restrict__ row_start,
                                                  const int* __restrict__ edge_src,
                                                  float* __restrict__ Z, int N) {
    int wave = threadIdx.x >> 6;
    int lane = threadIdx.x & 63;
    int node = blockIdx.x * 4 + wave;
    if (node >= N) return;
    int beg = row_start[node];
    int end = row_start[node + 1];
    const size_t base = (size_t)node * D;
    float acc0 = H[base + lane];
    float acc1 = 0.f;
    if constexpr (D == 128) acc1 = H[base + 64 + lane];
    int i = beg;
    for (; i + 4 <= end; i += 4) {
        int s0 = edge_src[i + 0];
        int s1 = edge_src[i + 1];
        int s2 = edge_src[i + 2];
        int s3 = edge_src[i + 3];
        float a = H[(size_t)s0 * D + lane] + H[(size_t)s1 * D + lane] +
                  H[(size_t)s2 * D + lane] + H[(size_t)s3 * D + lane];
        acc0 += a;
        if constexpr (D == 128) {
            float b = H[(size_t)s0 * D + 64 + lane] + H[(size_t)s1 * D + 64 + lane] +
                      H[(size_t)s2 * D + 64 + lane] + H[(size_t)s3 * D + 64 + lane];
            acc1 += b;
        }
    }
    for (; i < end; ++i) {
        int s = edge_src[i];
        acc0 += H[(size_t)s * D + lane];
        if constexpr (D == 128) acc1 += H[(size_t)s * D + 64 + lane];
    }
    Z[base + lane] = acc0;
    if constexpr (D == 128) Z[base + 64 + lane] = acc1;
}

// ---------------- weight prep: W[K][N] fp32 -> Wt[N][K] bf16 hi/lo ----------

__global__ __launch_bounds__(256) void prep_weights_kernel(const float* __restrict__ W1a,
                                                           const float* __restrict__ W1b,
                                                           const float* __restrict__ W2a,
                                                           const float* __restrict__ W2b,
                                                           const float* __restrict__ Wlin,
                                                           short* __restrict__ hi,
                                                           short* __restrict__ lo) {
    int i = blockIdx.x * 256 + threadIdx.x;   // 0..65535
    const float* W;
    int base, K, N;
    if (i < 8192)       { W = W1a;  base = 0;     K = 64;  N = 128; }
    else if (i < 24576) { W = W1b;  base = 8192;  K = 128; N = 128; }
    else if (i < 40960) { W = W2a;  base = 24576; K = 128; N = 128; }
    else if (i < 57344) { W = W2b;  base = 40960; K = 128; N = 128; }
    else                { W = Wlin; base = 57344; K = 128; N = 64;  }
    int rel = i - base;
    int n = rel / K;
    int k = rel - n * K;
    float v = W[k * N + n];
    unsigned p = bfpair(v);
    hi[i] = (short)(p & 0xffffu);
    lo[i] = (short)(p >> 16);
}

// ---------------- MFMA fused MLP --------------------------------------------
// LDS A-tile layout: dword ((T*KC + c)*8 + j)*66 + l holds (lo<<16)|hi of
// A[T*16 + (l&15)][c*32 + (l>>4)*8 + j].

template <int K>
__device__ inline void stage_global(const float* __restrict__ z, int M, int m0,
                                    unsigned* __restrict__ P, int t) {
    constexpr int KC = K / 32;
    constexpr int NF = 4 * KC * 64;
    #pragma unroll
    for (int fi = t; fi < NF; fi += 256) {
        int l = fi & 63;
        int tc = fi >> 6;
        int c = tc & (KC - 1);
        int T = tc / KC;
        int row = m0 + T * 16 + (l & 15);
        if (row >= M) row = M - 1;
        int kb = c * 32 + ((l >> 4) << 3);
        const float* p = z + (size_t)row * K + kb;
        float4 v0 = *reinterpret_cast<const float4*>(p);
        float4 v1 = *reinterpret_cast<const float4*>(p + 4);
        int base = ((T * KC + c) * 8) * 66 + l;
        P[base + 0 * 66] = bfpair(v0.x);
        P[base + 1 * 66] = bfpair(v0.y);
        P[base + 2 * 66] = bfpair(v0.z);
        P[base + 3 * 66] = bfpair(v0.w);
        P[base + 4 * 66] = bfpair(v1.x);
        P[base + 5 * 66] = bfpair(v1.y);
        P[base + 6 * 66] = bfpair(v1.z);
        P[base + 7 * 66] = bfpair(v1.w);
    }
}

// Software-pipelined: B-frags for groups of 4 n-tiles prefetched into a
// 2-deep register double buffer; loads for step s+1 issue before MFMAs of s.
template <int K, int NT>
__device__ inline void stage_compute(const unsigned* __restrict__ P,
                                     const short* __restrict__ WH,
                                     const short* __restrict__ WL,
                                     int w, int lane, f32x4* acc) {
    constexpr int KC = K / 32;
    constexpr int NG = (NT + 3) / 4;   // n-tile groups per k-chunk
    constexpr int TOT = KC * NG;
    const int q8 = (lane >> 4) << 3;
    const int ln = lane & 15;
    const size_t wrow = (size_t)ln * K;

    F8 bh[2][4], bl[2][4];
    auto load_grp = [&](int s, int buf) {
        const int c = s / NG, g = s % NG;
        const short* bp = WH + wrow + c * 32 + q8;
        const short* lp = WL + wrow + c * 32 + q8;
        #pragma unroll
        for (int j = 0; j < 4; ++j) {
            const size_t noff = (size_t)(g * 4 + j) * 16 * K;
            bh[buf][j].s = *reinterpret_cast<const short8*>(bp + noff);
            bl[buf][j].s = *reinterpret_cast<const short8*>(lp + noff);
        }
    };
    load_grp(0, 0);

    unsigned d[8];
    F8 ah, al;
    #pragma unroll
    for (int s = 0; s < TOT; ++s) {
        const int c = s / NG, g = s % NG;
        if (s + 1 < TOT) load_grp(s + 1, (s + 1) & 1);
        if (s % NG == 0) {   // new k-chunk: refresh A fragment (compile-time)
            int base = ((w * KC + c) * 8) * 66 + lane;
            #pragma unroll
            for (int j = 0; j < 8; ++j) d[j] = P[base + j * 66];
            #pragma unroll
            for (int j = 0; j < 4; ++j) {
                ah.u[j] = __builtin_amdgcn_perm(d[2 * j + 1], d[2 * j], 0x05040100u);
                al.u[j] = __builtin_amdgcn_perm(d[2 * j + 1], d[2 * j], 0x07060302u);
            }
        }
        #pragma unroll
        for (int j = 0; j < 4; ++j) {
            const int nt = g * 4 + j;
            if (nt < NT) {
                acc[nt] = __builtin_amdgcn_mfma_f32_16x16x32_bf16(ah.s, bh[s & 1][j].s, acc[nt], 0, 0, 0);
                acc[nt] = __builtin_amdgcn_mfma_f32_16x16x32_bf16(al.s, bh[s & 1][j].s, acc[nt], 0, 0, 0);
                acc[nt] = __builtin_amdgcn_mfma_f32_16x16x32_bf16(ah.s, bl[s & 1][j].s, acc[nt], 0, 0, 0);
            }
        }
    }
}

// bias + relu + C-layout -> next-stage A-frag layout (KC=4), into Pout
__device__ inline void epilogue_lds(const f32x4* acc, const float* __restrict__ bias,
                                    unsigned* __restrict__ Pout, int w, int lane) {
    int q = lane >> 4, ln = lane & 15;
    #pragma unroll
    for (int nt = 0; nt < 8; ++nt) {
        int col = nt * 16 + ln;
        float b = bias[col];
        int c = col >> 5, jj = col & 7, q2 = (col >> 3) & 3;
        int pb = ((w * 4 + c) * 8 + jj) * 66;
        #pragma unroll
        for (int r = 0; r < 4; ++r) {
            float v = fmaxf(acc[nt][r] + b, 0.f);
            Pout[pb + ((q * 4 + r) | (q2 << 4))] = bfpair(v);
        }
    }
}

// conv1 MLP: z[M,64] -> relu(relu(z@Wa+ba)@Wb+bb) = h1[M,128]
__global__ __launch_bounds__(256, 2) void mfma_mlp_A(const float* __restrict__ z,
                                                     const short* __restrict__ WaH,
                                                     const short* __restrict__ WaL,
                                                     const float* __restrict__ ba,
                                                     const short* __restrict__ WbH,
                                                     const short* __restrict__ WbL,
                                                     const float* __restrict__ bb,
                                                     float* __restrict__ Hout, int M) {
    __shared__ unsigned P[4 * 4 * 8 * 66];   // 33792 B, single buffer
    const int t = threadIdx.x;
    const int w = t >> 6, lane = t & 63;
    const int m0 = blockIdx.x * 64;
    const int q = lane >> 4, ln = lane & 15;

    stage_global<64>(z, M, m0, P, t);
    __syncthreads();

    f32x4 acc[8];
    #pragma unroll
    for (int i = 0; i < 8; ++i) acc[i] = (f32x4){0.f, 0.f, 0.f, 0.f};
    stage_compute<64, 8>(P, WaH, WaL, w, lane, acc);
    __syncthreads();                      // all reads of P done
    epilogue_lds(acc, ba, P, w, lane);    // overwrite P with stage-2 A-frags
    __syncthreads();

    #pragma unroll
    for (int i = 0; i < 8; ++i) acc[i] = (f32x4){0.f, 0.f, 0.f, 0.f};
    stage_compute<128, 8>(P, WbH, WbL, w, lane, acc);

    #pragma unroll
    for (int nt = 0; nt < 8; ++nt) {
        int col = nt * 16 + ln;
        float b = bb[col];
        #pragma unroll
        for (int r = 0; r < 4; ++r) {
            int row = m0 + w * 16 + q * 4 + r;
            if (row < M) Hout[(size_t)row * 128 + col] = fmaxf(acc[nt][r] + b, 0.f);
        }
    }
}

// conv2 MLP + head: z[M,128] -> (relu(relu(z@Wa+ba)@Wb+bb))@Wl+bl = out[M,64]
__global__ __launch_bounds__(256, 2) void mfma_mlp_B(const float* __restrict__ z,
                                                     const short* __restrict__ WaH,
                                                     const short* __restrict__ WaL,
                                                     const float* __restrict__ ba,
                                                     const short* __restrict__ WbH,
                                                     const short* __restrict__ WbL,
                                                     const float* __restrict__ bb,
                                                     const short* __restrict__ WlH,
                                                     const short* __restrict__ WlL,
                                                     const float* __restrict__ bl,
                                                     float* __restrict__ Out, int M) {
    __shared__ unsigned P[4 * 4 * 8 * 66];   // 33792 B, single buffer
    const int t = threadIdx.x;
    const int w = t >> 6, lane = t & 63;
    const int m0 = blockIdx.x * 64;
    const int q = lane >> 4, ln = lane & 15;

    stage_global<128>(z, M, m0, P, t);
    __syncthreads();

    f32x4 acc[8];
    #pragma unroll
    for (int i = 0; i < 8; ++i) acc[i] = (f32x4){0.f, 0.f, 0.f, 0.f};
    stage_compute<128, 8>(P, WaH, WaL, w, lane, acc);
    __syncthreads();
    epilogue_lds(acc, ba, P, w, lane);
    __syncthreads();

    #pragma unroll
    for (int i = 0; i < 8; ++i) acc[i] = (f32x4){0.f, 0.f, 0.f, 0.f};
    stage_compute<128, 8>(P, WbH, WbL, w, lane, acc);
    __syncthreads();
    epilogue_lds(acc, bb, P, w, lane);
    __syncthreads();

    f32x4 accC[4];
    #pragma unroll
    for (int i = 0; i < 4; ++i) accC[i] = (f32x4){0.f, 0.f, 0.f, 0.f};
    stage_compute<128, 4>(P, WlH, WlL, w, lane, accC);

    #pragma unroll
    for (int nt = 0; nt < 4; ++nt) {
        int col = nt * 16 + ln;
        float b = bl[col];
        #pragma unroll
        for (int r = 0; r < 4; ++r) {
            int row = m0 + w * 16 + q * 4 + r;
            if (row < M) Out[(size_t)row * 64 + col] = accC[nt][r] + b;
        }
    }
}

// ---------------------------------------------------------------------------

extern "C" void kernel_launch(void* const* d_in, const int* in_sizes, int n_in,
                              void* d_out, int out_size, void* d_ws, size_t ws_size,
                              hipStream_t stream) {
    const float* x    = (const float*)d_in[0];
    const int*   ei   = (const int*)d_in[1];
    const float* W1a  = (const float*)d_in[2];
    const float* b1a  = (const float*)d_in[3];
    const float* W1b  = (const float*)d_in[4];
    const float* b1b  = (const float*)d_in[5];
    const float* W2a  = (const float*)d_in[6];
    const float* b2a  = (const float*)d_in[7];
    const float* W2b  = (const float*)d_in[8];
    const float* b2b  = (const float*)d_in[9];
    const float* Wlin = (const float*)d_in[10];
    const float* blin = (const float*)d_in[11];
    float* out = (float*)d_out;

    const int N = in_sizes[0] / 64;   // 100000
    const int E = in_sizes[1] / 2;    // 1600000
    const int NBUCK = (N + BUCKET_NODES - 1) >> BUCKET_SHIFT;  // 196

    // workspace layout
    char* ws = (char*)d_ws;
    const size_t bufBytes = (size_t)N * 128 * sizeof(float);  // 51.2 MB
    float* A  = (float*)(ws + 0);
    float* B  = (float*)(ws + bufBytes);
    float* Cb = (float*)(ws + 2 * bufBytes);
    size_t off = 3 * bufBytes;
    int* row_start = (int*)(ws + off); off += ((size_t)(N + 1) * 4 + 15) & ~(size_t)15;
    int* cnt       = (int*)(ws + off); off += ((size_t)N * 4 + 15) & ~(size_t)15;
    int* partials  = (int*)(ws + off); off += 4096;
    int* gcur      = (int*)(ws + off); off += 4096;
    int* edge_src  = (int*)(ws + off); off += (size_t)E * 4;
    // CSR scratch aliases B[0 .. 16MB); bf16 weights alias B[32MB ..): disjoint.
    int* gsrc = (int*)B;
    int* gdst = (int*)B + (size_t)NBUCK * CAP;
    short* wHi = (short*)((char*)B + (32u << 20));
    short* wLo = wHi + 65536;
    short* w1aH = wHi + 0;     short* w1aL = wLo + 0;
    short* w1bH = wHi + 8192;  short* w1bL = wLo + 8192;
    short* w2aH = wHi + 24576; short* w2aL = wLo + 24576;
    short* w2bH = wHi + 40960; short* w2bL = wLo + 40960;
    short* wlH  = wHi + 57344; short* wlL  = wLo + 57344;

    const int NB_N = (N + 255) / 256;          // 391
    const int NB_A = (N + 3) / 4;              // 25000 agg blocks
    const int NB_G = (N + 63) / 64;            // 1563 MLP blocks
    const int NB_S = (E + EPB - 1) / EPB;      // 391 scatter blocks

    // 0. weight prep (independent of CSR chain)
    prep_weights_kernel<<<256, 256, 0, stream>>>(W1a, W1b, W2a, W2b, Wlin, wHi, wLo);

    // 1. CSR build, bucket-binned
    init_gcur_kernel<<<1, 256, 0, stream>>>(gcur, NBUCK);
    bucket_scatter_kernel<<<NB_S, 256, 0, stream>>>(ei, E, gcur, gsrc, gdst, NBUCK);
    bucket_hist_kernel<<<NBUCK, 256, 0, stream>>>(gdst, gcur, cnt, N);
    scan_block_kernel<<<NB_N, 256, 0, stream>>>(cnt, row_start, partials, N);
    scan_partials_kernel<<<1, 512, 0, stream>>>(partials, NB_N);
    scan_add_kernel<<<NB_N, 256, 0, stream>>>(row_start, partials, N, E);
    bucket_fill_kernel<<<NBUCK, 256, 0, stream>>>(gsrc, gdst, gcur, row_start, edge_src, N);

    // 2. conv1: agg + MFMA MLP
    agg_kernel<64><<<NB_A, 256, 0, stream>>>(x, row_start, edge_src, A, N);
    mfma_mlp_A<<<NB_G, 256, 0, stream>>>(A, w1aH, w1aL, b1a, w1bH, w1bL, b1b, Cb, N);

    // 3. conv2 + head: agg + MFMA MLP(+head)
    agg_kernel<128><<<NB_A, 256, 0, stream>>>(Cb, row_start, edge_src, A, N);
    mfma_mlp_B<<<NB_G, 256, 0, stream>>>(A, w2aH, w2aL, b2a, w2bH, w2bL, b2b,
                                         wlH, wlL, blin, out, N);
}

// Round 6
// 435.094 us; speedup vs baseline: 1.3312x; 1.2979x over previous
//
#include <hip/hip_runtime.h>

// ---------------------------------------------------------------------------
// GIN (2 GINConv layers + linear head) on MI355X.
// Round 6: fragment-interleaved weight layout. R5 post-mortem showed the
// compiler serialized per-lane B loads (VGPR=72) -> ~200cyc L2 wait per load.
// Now prep writes W so each B-fragment load is: one base pointer + lane*16B
// + immediate offset -> fully coalesced 1KB/instr, 16 independent loads per
// k-chunk, batched by the compiler into one waitcnt.
// CSR build + agg kernels unchanged.
// ---------------------------------------------------------------------------

typedef __attribute__((ext_vector_type(8))) short short8;
typedef __attribute__((ext_vector_type(4))) float f32x4;
union F8 { unsigned u[4]; short8 s; };

// pack float -> (lo bf16 << 16) | hi bf16, both RNE
__device__ inline unsigned bfpair(float v) {
    unsigned u = __float_as_uint(v);
    unsigned rh = u + 0x7fffu + ((u >> 16) & 1u);
    unsigned hf = rh & 0xffff0000u;              // hi rounded, as f32 bits
    float lof = v - __uint_as_float(hf);
    unsigned ul = __float_as_uint(lof);
    unsigned rl = ul + 0x7fffu + ((ul >> 16) & 1u);
    return (rh >> 16) | (rl & 0xffff0000u);
}

// ---------------- CSR build (unchanged) ----------------

constexpr int BUCKET_SHIFT = 9;
constexpr int BUCKET_NODES = 1 << BUCKET_SHIFT;
constexpr int CAP = 10240;
constexpr int EPB = 4096;
constexpr int NBUCK_MAX = 256;

__global__ __launch_bounds__(256) void init_gcur_kernel(int* __restrict__ gcur, int nbuck) {
    int i = threadIdx.x;
    if (i < nbuck) gcur[i] = i * CAP;
}

__global__ __launch_bounds__(256) void bucket_scatter_kernel(const int* __restrict__ ei, int E,
                                                             int* __restrict__ gcur,
                                                             int* __restrict__ gsrc,
                                                             int* __restrict__ gdst,
                                                             int nbuck) {
    __shared__ int ssrc[EPB];
    __shared__ int sdst[EPB];
    __shared__ int lcnt[NBUCK_MAX];
    __shared__ int lbase[NBUCK_MAX];
    __shared__ int lcur[NBUCK_MAX];
    __shared__ int gbase[NBUCK_MAX];
    __shared__ int stmp[256];

    const int t = threadIdx.x;
    const int e0 = blockIdx.x * EPB;
    const int ecnt = min(EPB, E - e0);

    for (int i = t; i < NBUCK_MAX; i += 256) lcnt[i] = 0;
    __syncthreads();

    for (int i = t; i < ecnt; i += 256) {
        int d = ei[E + e0 + i];
        atomicAdd(&lcnt[d >> BUCKET_SHIFT], 1);
    }
    __syncthreads();

    int v = lcnt[t];
    stmp[t] = v;
    __syncthreads();
    #pragma unroll
    for (int off = 1; off < 256; off <<= 1) {
        int add = (t >= off) ? stmp[t - off] : 0;
        __syncthreads();
        stmp[t] += add;
        __syncthreads();
    }
    lbase[t] = stmp[t] - v;
    lcur[t] = stmp[t] - v;
    __syncthreads();

    for (int i = t; i < ecnt; i += 256) {
        int s = ei[e0 + i];
        int d = ei[E + e0 + i];
        int p = atomicAdd(&lcur[d >> BUCKET_SHIFT], 1);
        ssrc[p] = s;
        sdst[p] = d;
    }
    __syncthreads();

    if (t < nbuck) {
        int c = lcnt[t];
        gbase[t] = (c > 0) ? atomicAdd(&gcur[t], c) : 0;
    }
    __syncthreads();

    for (int i = t; i < ecnt; i += 256) {
        int d = sdst[i];
        int b = d >> BUCKET_SHIFT;
        int gp = gbase[b] + (i - lbase[b]);
        if (gp < (b + 1) * CAP) {
            gsrc[gp] = ssrc[i];
            gdst[gp] = d;
        }
    }
}

__global__ __launch_bounds__(256) void bucket_hist_kernel(const int* __restrict__ gdst,
                                                          const int* __restrict__ gcur,
                                                          int* __restrict__ cnt, int N) {
    __shared__ int h[BUCKET_NODES];
    const int t = threadIdx.x;
    const int b = blockIdx.x;
    const int base = b << BUCKET_SHIFT;
    for (int i = t; i < BUCKET_NODES; i += 256) h[i] = 0;
    __syncthreads();
    int cb = min(gcur[b] - b * CAP, CAP);
    const int* dd = gdst + (size_t)b * CAP;
    for (int i = t; i < cb; i += 256) atomicAdd(&h[dd[i] - base], 1);
    __syncthreads();
    for (int i = t; i < BUCKET_NODES && base + i < N; i += 256) cnt[base + i] = h[i];
}

__global__ __launch_bounds__(256) void scan_block_kernel(const int* __restrict__ cnt,
                                                         int* __restrict__ rs,
                                                         int* __restrict__ partials,
                                                         int N) {
    __shared__ int s[256];
    int t = threadIdx.x;
    int i = blockIdx.x * 256 + t;
    int v = (i < N) ? cnt[i] : 0;
    s[t] = v;
    __syncthreads();
    #pragma unroll
    for (int off = 1; off < 256; off <<= 1) {
        int add = (t >= off) ? s[t - off] : 0;
        __syncthreads();
        s[t] += add;
        __syncthreads();
    }
    if (i < N) rs[i] = s[t] - v;
    if (t == 255) partials[blockIdx.x] = s[255];
}

__global__ __launch_bounds__(512) void scan_partials_kernel(int* __restrict__ partials,
                                                            int nb) {
    __shared__ int s[512];
    int t = threadIdx.x;
    int v = (t < nb) ? partials[t] : 0;
    s[t] = v;
    __syncthreads();
    #pragma unroll
    for (int off = 1; off < 512; off <<= 1) {
        int add = (t >= off) ? s[t - off] : 0;
        __syncthreads();
        s[t] += add;
        __syncthreads();
    }
    if (t < nb) partials[t] = s[t] - v;
}

__global__ __launch_bounds__(256) void scan_add_kernel(int* __restrict__ rs,
                                                       const int* __restrict__ partials,
                                                       int N, int E) {
    int i = blockIdx.x * 256 + threadIdx.x;
    if (i < N) rs[i] += partials[blockIdx.x];
    if (i == 0) rs[N] = E;
}

__global__ __launch_bounds__(256) void bucket_fill_kernel(const int* __restrict__ gsrc,
                                                          const int* __restrict__ gdst,
                                                          const int* __restrict__ gcur,
                                                          const int* __restrict__ rs,
                                                          int* __restrict__ edge_src, int N) {
    __shared__ int cur[BUCKET_NODES];
    const int t = threadIdx.x;
    const int b = blockIdx.x;
    const int base = b << BUCKET_SHIFT;
    for (int i = t; i < BUCKET_NODES; i += 256) cur[i] = rs[min(base + i, N)];
    __syncthreads();
    int cb = min(gcur[b] - b * CAP, CAP);
    const int* ss = gsrc + (size_t)b * CAP;
    const int* dd = gdst + (size_t)b * CAP;
    for (int i = t; i < cb; i += 256) {
        int d = dd[i];
        int s = ss[i];
        int p = atomicAdd(&cur[d - base], 1);
        edge_src[p] = s;
    }
}

// ---------------- aggregation (unchanged) ----------------

template <int D>
__global__ __launch_bounds__(256) void agg_kernel(const float* __restrict__ H,
                                                  const int* __restrict__ row_start,
                                                  const int* __restrict__ edge_src,
                                                  float* __restrict__ Z, int N) {
    int wave = threadIdx.x >> 6;
    int lane = threadIdx.x & 63;
    int node = blockIdx.x * 4 + wave;
    if (node >= N) return;
    int beg = row_start[node];
    int end = row_start[node + 1];
    const size_t base = (size_t)node * D;
    float acc0 = H[base + lane];
    float acc1 = 0.f;
    if constexpr (D == 128) acc1 = H[base + 64 + lane];
    int i = beg;
    for (; i + 4 <= end; i += 4) {
        int s0 = edge_src[i + 0];
        int s1 = edge_src[i + 1];
        int s2 = edge_src[i + 2];
        int s3 = edge_src[i + 3];
        float a = H[(size_t)s0 * D + lane] + H[(size_t)s1 * D + lane] +
                  H[(size_t)s2 * D + lane] + H[(size_t)s3 * D + lane];
        acc0 += a;
        if constexpr (D == 128) {
            float b = H[(size_t)s0 * D + 64 + lane] + H[(size_t)s1 * D + 64 + lane] +
                      H[(size_t)s2 * D + 64 + lane] + H[(size_t)s3 * D + 64 + lane];
            acc1 += b;
        }
    }
    for (; i < end; ++i) {
        int s = edge_src[i];
        acc0 += H[(size_t)s * D + lane];
        if constexpr (D == 128) acc1 += H[(size_t)s * D + 64 + lane];
    }
    Z[base + lane] = acc0;
    if constexpr (D == 128) Z[base + 64 + lane] = acc1;
}

// ---------------- weight prep: fragment-interleaved bf16 hi/lo --------------
// For a (K,NOUT) matrix: NT = NOUT/16 n-tiles, KC = K/32 k-chunks.
// Flat local index fi = ((c*NT + nt)*64 + l)*8 + j holds element
// W[k][n] with n = nt*16 + (l&15), k = c*32 + ((l>>4)<<3) + j.
// A lane's short8 B-fragment for (c,nt) is then contiguous at
// ((c*NT+nt)*64 + lane)*8 -> coalesced 1KB per wave load instruction.

__global__ __launch_bounds__(256) void prep_weights_kernel(const float* __restrict__ W1a,
                                                           const float* __restrict__ W1b,
                                                           const float* __restrict__ W2a,
                                                           const float* __restrict__ W2b,
                                                           const float* __restrict__ Wlin,
                                                           short* __restrict__ hi,
                                                           short* __restrict__ lo) {
    int i = blockIdx.x * 256 + threadIdx.x;   // 0..65535
    const float* W;
    int base, K, N;
    if (i < 8192)       { W = W1a;  base = 0;     K = 64;  N = 128; }
    else if (i < 24576) { W = W1b;  base = 8192;  K = 128; N = 128; }
    else if (i < 40960) { W = W2a;  base = 24576; K = 128; N = 128; }
    else if (i < 57344) { W = W2b;  base = 40960; K = 128; N = 128; }
    else                { W = Wlin; base = 57344; K = 128; N = 64;  }
    int rel = i - base;
    int NT = N >> 4;
    int j  = rel & 7;
    int l  = (rel >> 3) & 63;
    int tc = rel >> 9;            // c*NT + nt
    int nt = tc % NT;
    int c  = tc / NT;
    int n  = nt * 16 + (l & 15);
    int k  = c * 32 + ((l >> 4) << 3) + j;
    float v = W[k * N + n];
    unsigned p = bfpair(v);
    hi[i] = (short)(p & 0xffffu);
    lo[i] = (short)(p >> 16);
}

// ---------------- MFMA fused MLP --------------------------------------------
// LDS A-tile layout: dword ((T*KC + c)*8 + j)*66 + l holds (lo<<16)|hi of
// A[T*16 + (l&15)][c*32 + (l>>4)*8 + j].

template <int K>
__device__ inline void stage_global(const float* __restrict__ z, int M, int m0,
                                    unsigned* __restrict__ P, int t) {
    constexpr int KC = K / 32;
    constexpr int NF = 4 * KC * 64;
    #pragma unroll
    for (int fi = t; fi < NF; fi += 256) {
        int l = fi & 63;
        int tc = fi >> 6;
        int c = tc & (KC - 1);
        int T = tc / KC;
        int row = m0 + T * 16 + (l & 15);
        if (row >= M) row = M - 1;
        int kb = c * 32 + ((l >> 4) << 3);
        const float* p = z + (size_t)row * K + kb;
        float4 v0 = *reinterpret_cast<const float4*>(p);
        float4 v1 = *reinterpret_cast<const float4*>(p + 4);
        int base = ((T * KC + c) * 8) * 66 + l;
        P[base + 0 * 66] = bfpair(v0.x);
        P[base + 1 * 66] = bfpair(v0.y);
        P[base + 2 * 66] = bfpair(v0.z);
        P[base + 3 * 66] = bfpair(v0.w);
        P[base + 4 * 66] = bfpair(v1.x);
        P[base + 5 * 66] = bfpair(v1.y);
        P[base + 6 * 66] = bfpair(v1.z);
        P[base + 7 * 66] = bfpair(v1.w);
    }
}

// Per k-chunk: 8 ds_read + 8 perm (A), then NT*2 independent coalesced
// B-frag loads (single base + immediate offsets), then NT*3 MFMAs.
template <int K, int NT>
__device__ inline void stage_compute(const unsigned* __restrict__ P,
                                     const short* __restrict__ WH,
                                     const short* __restrict__ WL,
                                     int w, int lane, f32x4* acc) {
    constexpr int KC = K / 32;
    const unsigned* Pbase = P + (w * KC * 8) * 66 + lane;
    const short8* bhp = reinterpret_cast<const short8*>(WH) + lane;
    const short8* blp = reinterpret_cast<const short8*>(WL) + lane;
    for (int c = 0; c < KC; ++c) {
        unsigned d[8];
        #pragma unroll
        for (int j = 0; j < 8; ++j) d[j] = Pbase[(c * 8 + j) * 66];
        F8 ah, al;
        #pragma unroll
        for (int j = 0; j < 4; ++j) {
            ah.u[j] = __builtin_amdgcn_perm(d[2 * j + 1], d[2 * j], 0x05040100u);
            al.u[j] = __builtin_amdgcn_perm(d[2 * j + 1], d[2 * j], 0x07060302u);
        }
        F8 bh[NT], bl[NT];
        #pragma unroll
        for (int nt = 0; nt < NT; ++nt) {
            bh[nt].s = bhp[(c * NT + nt) * 64];
            bl[nt].s = blp[(c * NT + nt) * 64];
        }
        #pragma unroll
        for (int nt = 0; nt < NT; ++nt) {
            acc[nt] = __builtin_amdgcn_mfma_f32_16x16x32_bf16(ah.s, bh[nt].s, acc[nt], 0, 0, 0);
            acc[nt] = __builtin_amdgcn_mfma_f32_16x16x32_bf16(al.s, bh[nt].s, acc[nt], 0, 0, 0);
            acc[nt] = __builtin_amdgcn_mfma_f32_16x16x32_bf16(ah.s, bl[nt].s, acc[nt], 0, 0, 0);
        }
    }
}

// bias + relu + C-layout -> next-stage A-frag layout (KC=4), into Pout
__device__ inline void epilogue_lds(const f32x4* acc, const float* __restrict__ bias,
                                    unsigned* __restrict__ Pout, int w, int lane) {
    int q = lane >> 4, ln = lane & 15;
    #pragma unroll
    for (int nt = 0; nt < 8; ++nt) {
        int col = nt * 16 + ln;
        float b = bias[col];
        int c = col >> 5, jj = col & 7, q2 = (col >> 3) & 3;
        int pb = ((w * 4 + c) * 8 + jj) * 66;
        #pragma unroll
        for (int r = 0; r < 4; ++r) {
            float v = fmaxf(acc[nt][r] + b, 0.f);
            Pout[pb + ((q * 4 + r) | (q2 << 4))] = bfpair(v);
        }
    }
}

// conv1 MLP: z[M,64] -> relu(relu(z@Wa+ba)@Wb+bb) = h1[M,128]
__global__ __launch_bounds__(256, 2) void mfma_mlp_A(const float* __restrict__ z,
                                                     const short* __restrict__ WaH,
                                                     const short* __restrict__ WaL,
                                                     const float* __restrict__ ba,
                                                     const short* __restrict__ WbH,
                                                     const short* __restrict__ WbL,
                                                     const float* __restrict__ bb,
                                                     float* __restrict__ Hout, int M) {
    __shared__ unsigned P[4 * 4 * 8 * 66];   // 33792 B, single buffer
    const int t = threadIdx.x;
    const int w = t >> 6, lane = t & 63;
    const int m0 = blockIdx.x * 64;
    const int q = lane >> 4, ln = lane & 15;

    stage_global<64>(z, M, m0, P, t);
    __syncthreads();

    f32x4 acc[8];
    #pragma unroll
    for (int i = 0; i < 8; ++i) acc[i] = (f32x4){0.f, 0.f, 0.f, 0.f};
    stage_compute<64, 8>(P, WaH, WaL, w, lane, acc);
    __syncthreads();                      // all reads of P done
    epilogue_lds(acc, ba, P, w, lane);    // overwrite P with stage-2 A-frags
    __syncthreads();

    #pragma unroll
    for (int i = 0; i < 8; ++i) acc[i] = (f32x4){0.f, 0.f, 0.f, 0.f};
    stage_compute<128, 8>(P, WbH, WbL, w, lane, acc);

    #pragma unroll
    for (int nt = 0; nt < 8; ++nt) {
        int col = nt * 16 + ln;
        float b = bb[col];
        #pragma unroll
        for (int r = 0; r < 4; ++r) {
            int row = m0 + w * 16 + q * 4 + r;
            if (row < M) Hout[(size_t)row * 128 + col] = fmaxf(acc[nt][r] + b, 0.f);
        }
    }
}

// conv2 MLP + head: z[M,128] -> (relu(relu(z@Wa+ba)@Wb+bb))@Wl+bl = out[M,64]
__global__ __launch_bounds__(256, 2) void mfma_mlp_B(const float* __restrict__ z,
                                                     const short* __restrict__ WaH,
                                                     const short* __restrict__ WaL,
                                                     const float* __restrict__ ba,
                                                     const short* __restrict__ WbH,
                                                     const short* __restrict__ WbL,
                                                     const float* __restrict__ bb,
                                                     const short* __restrict__ WlH,
                                                     const short* __restrict__ WlL,
                                                     const float* __restrict__ bl,
                                                     float* __restrict__ Out, int M) {
    __shared__ unsigned P[4 * 4 * 8 * 66];   // 33792 B, single buffer
    const int t = threadIdx.x;
    const int w = t >> 6, lane = t & 63;
    const int m0 = blockIdx.x * 64;
    const int q = lane >> 4, ln = lane & 15;

    stage_global<128>(z, M, m0, P, t);
    __syncthreads();

    f32x4 acc[8];
    #pragma unroll
    for (int i = 0; i < 8; ++i) acc[i] = (f32x4){0.f, 0.f, 0.f, 0.f};
    stage_compute<128, 8>(P, WaH, WaL, w, lane, acc);
    __syncthreads();
    epilogue_lds(acc, ba, P, w, lane);
    __syncthreads();

    #pragma unroll
    for (int i = 0; i < 8; ++i) acc[i] = (f32x4){0.f, 0.f, 0.f, 0.f};
    stage_compute<128, 8>(P, WbH, WbL, w, lane, acc);
    __syncthreads();
    epilogue_lds(acc, bb, P, w, lane);
    __syncthreads();

    f32x4 accC[4];
    #pragma unroll
    for (int i = 0; i < 4; ++i) accC[i] = (f32x4){0.f, 0.f, 0.f, 0.f};
    stage_compute<128, 4>(P, WlH, WlL, w, lane, accC);

    #pragma unroll
    for (int nt = 0; nt < 4; ++nt) {
        int col = nt * 16 + ln;
        float b = bl[col];
        #pragma unroll
        for (int r = 0; r < 4; ++r) {
            int row = m0 + w * 16 + q * 4 + r;
            if (row < M) Out[(size_t)row * 64 + col] = accC[nt][r] + b;
        }
    }
}

// ---------------------------------------------------------------------------

extern "C" void kernel_launch(void* const* d_in, const int* in_sizes, int n_in,
                              void* d_out, int out_size, void* d_ws, size_t ws_size,
                              hipStream_t stream) {
    const float* x    = (const float*)d_in[0];
    const int*   ei   = (const int*)d_in[1];
    const float* W1a  = (const float*)d_in[2];
    const float* b1a  = (const float*)d_in[3];
    const float* W1b  = (const float*)d_in[4];
    const float* b1b  = (const float*)d_in[5];
    const float* W2a  = (const float*)d_in[6];
    const float* b2a  = (const float*)d_in[7];
    const float* W2b  = (const float*)d_in[8];
    const float* b2b  = (const float*)d_in[9];
    const float* Wlin = (const float*)d_in[10];
    const float* blin = (const float*)d_in[11];
    float* out = (float*)d_out;

    const int N = in_sizes[0] / 64;   // 100000
    const int E = in_sizes[1] / 2;    // 1600000
    const int NBUCK = (N + BUCKET_NODES - 1) >> BUCKET_SHIFT;  // 196

    // workspace layout
    char* ws = (char*)d_ws;
    const size_t bufBytes = (size_t)N * 128 * sizeof(float);  // 51.2 MB
    float* A  = (float*)(ws + 0);
    float* B  = (float*)(ws + bufBytes);
    float* Cb = (float*)(ws + 2 * bufBytes);
    size_t off = 3 * bufBytes;
    int* row_start = (int*)(ws + off); off += ((size_t)(N + 1) * 4 + 15) & ~(size_t)15;
    int* cnt       = (int*)(ws + off); off += ((size_t)N * 4 + 15) & ~(size_t)15;
    int* partials  = (int*)(ws + off); off += 4096;
    int* gcur      = (int*)(ws + off); off += 4096;
    int* edge_src  = (int*)(ws + off); off += (size_t)E * 4;
    // CSR scratch aliases B[0 .. 16MB); bf16 weights alias B[32MB ..): disjoint.
    int* gsrc = (int*)B;
    int* gdst = (int*)B + (size_t)NBUCK * CAP;
    short* wHi = (short*)((char*)B + (32u << 20));
    short* wLo = wHi + 65536;
    short* w1aH = wHi + 0;     short* w1aL = wLo + 0;
    short* w1bH = wHi + 8192;  short* w1bL = wLo + 8192;
    short* w2aH = wHi + 24576; short* w2aL = wLo + 24576;
    short* w2bH = wHi + 40960; short* w2bL = wLo + 40960;
    short* wlH  = wHi + 57344; short* wlL  = wLo + 57344;

    const int NB_N = (N + 255) / 256;          // 391
    const int NB_A = (N + 3) / 4;              // 25000 agg blocks
    const int NB_G = (N + 63) / 64;            // 1563 MLP blocks
    const int NB_S = (E + EPB - 1) / EPB;      // 391 scatter blocks

    // 0. weight prep (independent of CSR chain)
    prep_weights_kernel<<<256, 256, 0, stream>>>(W1a, W1b, W2a, W2b, Wlin, wHi, wLo);

    // 1. CSR build, bucket-binned
    init_gcur_kernel<<<1, 256, 0, stream>>>(gcur, NBUCK);
    bucket_scatter_kernel<<<NB_S, 256, 0, stream>>>(ei, E, gcur, gsrc, gdst, NBUCK);
    bucket_hist_kernel<<<NBUCK, 256, 0, stream>>>(gdst, gcur, cnt, N);
    scan_block_kernel<<<NB_N, 256, 0, stream>>>(cnt, row_start, partials, N);
    scan_partials_kernel<<<1, 512, 0, stream>>>(partials, NB_N);
    scan_add_kernel<<<NB_N, 256, 0, stream>>>(row_start, partials, N, E);
    bucket_fill_kernel<<<NBUCK, 256, 0, stream>>>(gsrc, gdst, gcur, row_start, edge_src, N);

    // 2. conv1: agg + MFMA MLP
    agg_kernel<64><<<NB_A, 256, 0, stream>>>(x, row_start, edge_src, A, N);
    mfma_mlp_A<<<NB_G, 256, 0, stream>>>(A, w1aH, w1aL, b1a, w1bH, w1bL, b1b, Cb, N);

    // 3. conv2 + head: agg + MFMA MLP(+head)
    agg_kernel<128><<<NB_A, 256, 0, stream>>>(Cb, row_start, edge_src, A, N);
    mfma_mlp_B<<<NB_G, 256, 0, stream>>>(A, w2aH, w2aL, b2a, w2bH, w2bL, b2b,
                                         wlH, wlL, blin, out, N);
}

// Round 7
// 401.371 us; speedup vs baseline: 1.4430x; 1.0840x over previous
//
#include <hip/hip_runtime.h>
#include <hip/hip_fp16.h>

// ---------------------------------------------------------------------------
// GIN (2 GINConv layers + linear head) on MI355X.
// Round 7: fp16 gather path for aggregation. R6 counters: agg<128> FETCH
// 400MB = 8 XCDs x 51.2MB fp32 H (L2 can't hold it). Gathers now read an
// fp16 shadow (half the bytes, half the loads: one dword = 2 cols per lane);
// self-term and all GEMM math stay fp32/split-bf16 exact.
//   - x -> fp16 via convert kernel (into dead B-buffer space)
//   - h1 -> fp16 written by mfma_mlp_A epilogue alongside fp32
//   - agg64: 2 nodes per wave (32-lane groups, 128B coalesced gathers)
// CSR build + MLP structure unchanged from round 6.
// ---------------------------------------------------------------------------

typedef __attribute__((ext_vector_type(8))) short short8;
typedef __attribute__((ext_vector_type(4))) float f32x4;
union F8 { unsigned u[4]; short8 s; };

// pack float -> (lo bf16 << 16) | hi bf16, both RNE
__device__ inline unsigned bfpair(float v) {
    unsigned u = __float_as_uint(v);
    unsigned rh = u + 0x7fffu + ((u >> 16) & 1u);
    unsigned hf = rh & 0xffff0000u;              // hi rounded, as f32 bits
    float lof = v - __uint_as_float(hf);
    unsigned ul = __float_as_uint(lof);
    unsigned rl = ul + 0x7fffu + ((ul >> 16) & 1u);
    return (rh >> 16) | (rl & 0xffff0000u);
}

// ---------------- CSR build (unchanged) ----------------

constexpr int BUCKET_SHIFT = 9;
constexpr int BUCKET_NODES = 1 << BUCKET_SHIFT;
constexpr int CAP = 10240;
constexpr int EPB = 4096;
constexpr int NBUCK_MAX = 256;

__global__ __launch_bounds__(256) void init_gcur_kernel(int* __restrict__ gcur, int nbuck) {
    int i = threadIdx.x;
    if (i < nbuck) gcur[i] = i * CAP;
}

__global__ __launch_bounds__(256) void bucket_scatter_kernel(const int* __restrict__ ei, int E,
                                                             int* __restrict__ gcur,
                                                             int* __restrict__ gsrc,
                                                             int* __restrict__ gdst,
                                                             int nbuck) {
    __shared__ int ssrc[EPB];
    __shared__ int sdst[EPB];
    __shared__ int lcnt[NBUCK_MAX];
    __shared__ int lbase[NBUCK_MAX];
    __shared__ int lcur[NBUCK_MAX];
    __shared__ int gbase[NBUCK_MAX];
    __shared__ int stmp[256];

    const int t = threadIdx.x;
    const int e0 = blockIdx.x * EPB;
    const int ecnt = min(EPB, E - e0);

    for (int i = t; i < NBUCK_MAX; i += 256) lcnt[i] = 0;
    __syncthreads();

    for (int i = t; i < ecnt; i += 256) {
        int d = ei[E + e0 + i];
        atomicAdd(&lcnt[d >> BUCKET_SHIFT], 1);
    }
    __syncthreads();

    int v = lcnt[t];
    stmp[t] = v;
    __syncthreads();
    #pragma unroll
    for (int off = 1; off < 256; off <<= 1) {
        int add = (t >= off) ? stmp[t - off] : 0;
        __syncthreads();
        stmp[t] += add;
        __syncthreads();
    }
    lbase[t] = stmp[t] - v;
    lcur[t] = stmp[t] - v;
    __syncthreads();

    for (int i = t; i < ecnt; i += 256) {
        int s = ei[e0 + i];
        int d = ei[E + e0 + i];
        int p = atomicAdd(&lcur[d >> BUCKET_SHIFT], 1);
        ssrc[p] = s;
        sdst[p] = d;
    }
    __syncthreads();

    if (t < nbuck) {
        int c = lcnt[t];
        gbase[t] = (c > 0) ? atomicAdd(&gcur[t], c) : 0;
    }
    __syncthreads();

    for (int i = t; i < ecnt; i += 256) {
        int d = sdst[i];
        int b = d >> BUCKET_SHIFT;
        int gp = gbase[b] + (i - lbase[b]);
        if (gp < (b + 1) * CAP) {
            gsrc[gp] = ssrc[i];
            gdst[gp] = d;
        }
    }
}

__global__ __launch_bounds__(256) void bucket_hist_kernel(const int* __restrict__ gdst,
                                                          const int* __restrict__ gcur,
                                                          int* __restrict__ cnt, int N) {
    __shared__ int h[BUCKET_NODES];
    const int t = threadIdx.x;
    const int b = blockIdx.x;
    const int base = b << BUCKET_SHIFT;
    for (int i = t; i < BUCKET_NODES; i += 256) h[i] = 0;
    __syncthreads();
    int cb = min(gcur[b] - b * CAP, CAP);
    const int* dd = gdst + (size_t)b * CAP;
    for (int i = t; i < cb; i += 256) atomicAdd(&h[dd[i] - base], 1);
    __syncthreads();
    for (int i = t; i < BUCKET_NODES && base + i < N; i += 256) cnt[base + i] = h[i];
}

__global__ __launch_bounds__(256) void scan_block_kernel(const int* __restrict__ cnt,
                                                         int* __restrict__ rs,
                                                         int* __restrict__ partials,
                                                         int N) {
    __shared__ int s[256];
    int t = threadIdx.x;
    int i = blockIdx.x * 256 + t;
    int v = (i < N) ? cnt[i] : 0;
    s[t] = v;
    __syncthreads();
    #pragma unroll
    for (int off = 1; off < 256; off <<= 1) {
        int add = (t >= off) ? s[t - off] : 0;
        __syncthreads();
        s[t] += add;
        __syncthreads();
    }
    if (i < N) rs[i] = s[t] - v;
    if (t == 255) partials[blockIdx.x] = s[255];
}

__global__ __launch_bounds__(512) void scan_partials_kernel(int* __restrict__ partials,
                                                            int nb) {
    __shared__ int s[512];
    int t = threadIdx.x;
    int v = (t < nb) ? partials[t] : 0;
    s[t] = v;
    __syncthreads();
    #pragma unroll
    for (int off = 1; off < 512; off <<= 1) {
        int add = (t >= off) ? s[t - off] : 0;
        __syncthreads();
        s[t] += add;
        __syncthreads();
    }
    if (t < nb) partials[t] = s[t] - v;
}

__global__ __launch_bounds__(256) void scan_add_kernel(int* __restrict__ rs,
                                                       const int* __restrict__ partials,
                                                       int N, int E) {
    int i = blockIdx.x * 256 + threadIdx.x;
    if (i < N) rs[i] += partials[blockIdx.x];
    if (i == 0) rs[N] = E;
}

__global__ __launch_bounds__(256) void bucket_fill_kernel(const int* __restrict__ gsrc,
                                                          const int* __restrict__ gdst,
                                                          const int* __restrict__ gcur,
                                                          const int* __restrict__ rs,
                                                          int* __restrict__ edge_src, int N) {
    __shared__ int cur[BUCKET_NODES];
    const int t = threadIdx.x;
    const int b = blockIdx.x;
    const int base = b << BUCKET_SHIFT;
    for (int i = t; i < BUCKET_NODES; i += 256) cur[i] = rs[min(base + i, N)];
    __syncthreads();
    int cb = min(gcur[b] - b * CAP, CAP);
    const int* ss = gsrc + (size_t)b * CAP;
    const int* dd = gdst + (size_t)b * CAP;
    for (int i = t; i < cb; i += 256) {
        int d = dd[i];
        int s = ss[i];
        int p = atomicAdd(&cur[d - base], 1);
        edge_src[p] = s;
    }
}

// ---------------- fp16 convert + aggregation ----------------

__global__ __launch_bounds__(256) void convert_fp16_kernel(const float* __restrict__ src,
                                                           __half2* __restrict__ dst, int n2) {
    int i = blockIdx.x * 256 + threadIdx.x;
    if (i < n2) {
        float2 v = reinterpret_cast<const float2*>(src)[i];
        dst[i] = __floats2half2_rn(v.x, v.y);
    }
}

// Z[i] = Hf[i] + sum_j fp16(H[src_j]);  D=128, one wave per node,
// lane l covers cols (2l, 2l+1) via one dword gather per edge.
__global__ __launch_bounds__(256) void agg128_fp16(const float* __restrict__ Hf,
                                                   const __half2* __restrict__ H16,
                                                   const int* __restrict__ row_start,
                                                   const int* __restrict__ edge_src,
                                                   float* __restrict__ Z, int N) {
    int wave = threadIdx.x >> 6, lane = threadIdx.x & 63;
    int node = blockIdx.x * 4 + wave;
    if (node >= N) return;
    int beg = row_start[node], end = row_start[node + 1];
    float2 self = reinterpret_cast<const float2*>(Hf + (size_t)node * 128)[lane];
    float a0 = self.x, a1 = self.y;
    int i = beg;
    for (; i + 4 <= end; i += 4) {
        int s0 = edge_src[i], s1 = edge_src[i + 1];
        int s2 = edge_src[i + 2], s3 = edge_src[i + 3];
        float2 v0 = __half22float2(H16[(size_t)s0 * 64 + lane]);
        float2 v1 = __half22float2(H16[(size_t)s1 * 64 + lane]);
        float2 v2 = __half22float2(H16[(size_t)s2 * 64 + lane]);
        float2 v3 = __half22float2(H16[(size_t)s3 * 64 + lane]);
        a0 += (v0.x + v1.x) + (v2.x + v3.x);
        a1 += (v0.y + v1.y) + (v2.y + v3.y);
    }
    for (; i < end; ++i) {
        float2 v = __half22float2(H16[(size_t)edge_src[i] * 64 + lane]);
        a0 += v.x;
        a1 += v.y;
    }
    float2 o; o.x = a0; o.y = a1;
    reinterpret_cast<float2*>(Z + (size_t)node * 128)[lane] = o;
}

// D=64: two nodes per wave (32-lane groups, 128B coalesced gathers).
__global__ __launch_bounds__(256) void agg64_fp16(const float* __restrict__ Hf,
                                                  const __half2* __restrict__ H16,
                                                  const int* __restrict__ row_start,
                                                  const int* __restrict__ edge_src,
                                                  float* __restrict__ Z, int N) {
    int t = threadIdx.x;
    int grp = t >> 5;          // 0..7
    int gl = t & 31;
    int node = blockIdx.x * 8 + grp;
    if (node >= N) return;
    int beg = row_start[node], end = row_start[node + 1];
    float2 self = reinterpret_cast<const float2*>(Hf + (size_t)node * 64)[gl];
    float a0 = self.x, a1 = self.y;
    int i = beg;
    for (; i + 4 <= end; i += 4) {
        int s0 = edge_src[i], s1 = edge_src[i + 1];
        int s2 = edge_src[i + 2], s3 = edge_src[i + 3];
        float2 v0 = __half22float2(H16[(size_t)s0 * 32 + gl]);
        float2 v1 = __half22float2(H16[(size_t)s1 * 32 + gl]);
        float2 v2 = __half22float2(H16[(size_t)s2 * 32 + gl]);
        float2 v3 = __half22float2(H16[(size_t)s3 * 32 + gl]);
        a0 += (v0.x + v1.x) + (v2.x + v3.x);
        a1 += (v0.y + v1.y) + (v2.y + v3.y);
    }
    for (; i < end; ++i) {
        float2 v = __half22float2(H16[(size_t)edge_src[i] * 32 + gl]);
        a0 += v.x;
        a1 += v.y;
    }
    float2 o; o.x = a0; o.y = a1;
    reinterpret_cast<float2*>(Z + (size_t)node * 64)[gl] = o;
}

// ---------------- weight prep: fragment-interleaved bf16 hi/lo --------------

__global__ __launch_bounds__(256) void prep_weights_kernel(const float* __restrict__ W1a,
                                                           const float* __restrict__ W1b,
                                                           const float* __restrict__ W2a,
                                                           const float* __restrict__ W2b,
                                                           const float* __restrict__ Wlin,
                                                           short* __restrict__ hi,
                                                           short* __restrict__ lo) {
    int i = blockIdx.x * 256 + threadIdx.x;   // 0..65535
    const float* W;
    int base, K, N;
    if (i < 8192)       { W = W1a;  base = 0;     K = 64;  N = 128; }
    else if (i < 24576) { W = W1b;  base = 8192;  K = 128; N = 128; }
    else if (i < 40960) { W = W2a;  base = 24576; K = 128; N = 128; }
    else if (i < 57344) { W = W2b;  base = 40960; K = 128; N = 128; }
    else                { W = Wlin; base = 57344; K = 128; N = 64;  }
    int rel = i - base;
    int NT = N >> 4;
    int j  = rel & 7;
    int l  = (rel >> 3) & 63;
    int tc = rel >> 9;            // c*NT + nt
    int nt = tc % NT;
    int c  = tc / NT;
    int n  = nt * 16 + (l & 15);
    int k  = c * 32 + ((l >> 4) << 3) + j;
    float v = W[k * N + n];
    unsigned p = bfpair(v);
    hi[i] = (short)(p & 0xffffu);
    lo[i] = (short)(p >> 16);
}

// ---------------- MFMA fused MLP --------------------------------------------

template <int K>
__device__ inline void stage_global(const float* __restrict__ z, int M, int m0,
                                    unsigned* __restrict__ P, int t) {
    constexpr int KC = K / 32;
    constexpr int NF = 4 * KC * 64;
    #pragma unroll
    for (int fi = t; fi < NF; fi += 256) {
        int l = fi & 63;
        int tc = fi >> 6;
        int c = tc & (KC - 1);
        int T = tc / KC;
        int row = m0 + T * 16 + (l & 15);
        if (row >= M) row = M - 1;
        int kb = c * 32 + ((l >> 4) << 3);
        const float* p = z + (size_t)row * K + kb;
        float4 v0 = *reinterpret_cast<const float4*>(p);
        float4 v1 = *reinterpret_cast<const float4*>(p + 4);
        int base = ((T * KC + c) * 8) * 66 + l;
        P[base + 0 * 66] = bfpair(v0.x);
        P[base + 1 * 66] = bfpair(v0.y);
        P[base + 2 * 66] = bfpair(v0.z);
        P[base + 3 * 66] = bfpair(v0.w);
        P[base + 4 * 66] = bfpair(v1.x);
        P[base + 5 * 66] = bfpair(v1.y);
        P[base + 6 * 66] = bfpair(v1.z);
        P[base + 7 * 66] = bfpair(v1.w);
    }
}

template <int K, int NT>
__device__ inline void stage_compute(const unsigned* __restrict__ P,
                                     const short* __restrict__ WH,
                                     const short* __restrict__ WL,
                                     int w, int lane, f32x4* acc) {
    constexpr int KC = K / 32;
    const unsigned* Pbase = P + (w * KC * 8) * 66 + lane;
    const short8* bhp = reinterpret_cast<const short8*>(WH) + lane;
    const short8* blp = reinterpret_cast<const short8*>(WL) + lane;
    for (int c = 0; c < KC; ++c) {
        unsigned d[8];
        #pragma unroll
        for (int j = 0; j < 8; ++j) d[j] = Pbase[(c * 8 + j) * 66];
        F8 ah, al;
        #pragma unroll
        for (int j = 0; j < 4; ++j) {
            ah.u[j] = __builtin_amdgcn_perm(d[2 * j + 1], d[2 * j], 0x05040100u);
            al.u[j] = __builtin_amdgcn_perm(d[2 * j + 1], d[2 * j], 0x07060302u);
        }
        F8 bh[NT], bl[NT];
        #pragma unroll
        for (int nt = 0; nt < NT; ++nt) {
            bh[nt].s = bhp[(c * NT + nt) * 64];
            bl[nt].s = blp[(c * NT + nt) * 64];
        }
        #pragma unroll
        for (int nt = 0; nt < NT; ++nt) {
            acc[nt] = __builtin_amdgcn_mfma_f32_16x16x32_bf16(ah.s, bh[nt].s, acc[nt], 0, 0, 0);
            acc[nt] = __builtin_amdgcn_mfma_f32_16x16x32_bf16(al.s, bh[nt].s, acc[nt], 0, 0, 0);
            acc[nt] = __builtin_amdgcn_mfma_f32_16x16x32_bf16(ah.s, bl[nt].s, acc[nt], 0, 0, 0);
        }
    }
}

__device__ inline void epilogue_lds(const f32x4* acc, const float* __restrict__ bias,
                                    unsigned* __restrict__ Pout, int w, int lane) {
    int q = lane >> 4, ln = lane & 15;
    #pragma unroll
    for (int nt = 0; nt < 8; ++nt) {
        int col = nt * 16 + ln;
        float b = bias[col];
        int c = col >> 5, jj = col & 7, q2 = (col >> 3) & 3;
        int pb = ((w * 4 + c) * 8 + jj) * 66;
        #pragma unroll
        for (int r = 0; r < 4; ++r) {
            float v = fmaxf(acc[nt][r] + b, 0.f);
            Pout[pb + ((q * 4 + r) | (q2 << 4))] = bfpair(v);
        }
    }
}

// conv1 MLP: z[M,64] -> relu(relu(z@Wa+ba)@Wb+bb) = h1 (fp32 + fp16 shadow)
__global__ __launch_bounds__(256, 2) void mfma_mlp_A(const float* __restrict__ z,
                                                     const short* __restrict__ WaH,
                                                     const short* __restrict__ WaL,
                                                     const float* __restrict__ ba,
                                                     const short* __restrict__ WbH,
                                                     const short* __restrict__ WbL,
                                                     const float* __restrict__ bb,
                                                     float* __restrict__ Hout,
                                                     __half* __restrict__ H16out, int M) {
    __shared__ unsigned P[4 * 4 * 8 * 66];   // 33792 B, single buffer
    const int t = threadIdx.x;
    const int w = t >> 6, lane = t & 63;
    const int m0 = blockIdx.x * 64;
    const int q = lane >> 4, ln = lane & 15;

    stage_global<64>(z, M, m0, P, t);
    __syncthreads();

    f32x4 acc[8];
    #pragma unroll
    for (int i = 0; i < 8; ++i) acc[i] = (f32x4){0.f, 0.f, 0.f, 0.f};
    stage_compute<64, 8>(P, WaH, WaL, w, lane, acc);
    __syncthreads();
    epilogue_lds(acc, ba, P, w, lane);
    __syncthreads();

    #pragma unroll
    for (int i = 0; i < 8; ++i) acc[i] = (f32x4){0.f, 0.f, 0.f, 0.f};
    stage_compute<128, 8>(P, WbH, WbL, w, lane, acc);

    #pragma unroll
    for (int nt = 0; nt < 8; ++nt) {
        int col = nt * 16 + ln;
        float b = bb[col];
        #pragma unroll
        for (int r = 0; r < 4; ++r) {
            int row = m0 + w * 16 + q * 4 + r;
            if (row < M) {
                float v = fmaxf(acc[nt][r] + b, 0.f);
                Hout[(size_t)row * 128 + col] = v;
                H16out[(size_t)row * 128 + col] = __float2half_rn(v);
            }
        }
    }
}

// conv2 MLP + head
__global__ __launch_bounds__(256, 2) void mfma_mlp_B(const float* __restrict__ z,
                                                     const short* __restrict__ WaH,
                                                     const short* __restrict__ WaL,
                                                     const float* __restrict__ ba,
                                                     const short* __restrict__ WbH,
                                                     const short* __restrict__ WbL,
                                                     const float* __restrict__ bb,
                                                     const short* __restrict__ WlH,
                                                     const short* __restrict__ WlL,
                                                     const float* __restrict__ bl,
                                                     float* __restrict__ Out, int M) {
    __shared__ unsigned P[4 * 4 * 8 * 66];   // 33792 B, single buffer
    const int t = threadIdx.x;
    const int w = t >> 6, lane = t & 63;
    const int m0 = blockIdx.x * 64;
    const int q = lane >> 4, ln = lane & 15;

    stage_global<128>(z, M, m0, P, t);
    __syncthreads();

    f32x4 acc[8];
    #pragma unroll
    for (int i = 0; i < 8; ++i) acc[i] = (f32x4){0.f, 0.f, 0.f, 0.f};
    stage_compute<128, 8>(P, WaH, WaL, w, lane, acc);
    __syncthreads();
    epilogue_lds(acc, ba, P, w, lane);
    __syncthreads();

    #pragma unroll
    for (int i = 0; i < 8; ++i) acc[i] = (f32x4){0.f, 0.f, 0.f, 0.f};
    stage_compute<128, 8>(P, WbH, WbL, w, lane, acc);
    __syncthreads();
    epilogue_lds(acc, bb, P, w, lane);
    __syncthreads();

    f32x4 accC[4];
    #pragma unroll
    for (int i = 0; i < 4; ++i) accC[i] = (f32x4){0.f, 0.f, 0.f, 0.f};
    stage_compute<128, 4>(P, WlH, WlL, w, lane, accC);

    #pragma unroll
    for (int nt = 0; nt < 4; ++nt) {
        int col = nt * 16 + ln;
        float b = bl[col];
        #pragma unroll
        for (int r = 0; r < 4; ++r) {
            int row = m0 + w * 16 + q * 4 + r;
            if (row < M) Out[(size_t)row * 64 + col] = accC[nt][r] + b;
        }
    }
}

// ---------------------------------------------------------------------------

extern "C" void kernel_launch(void* const* d_in, const int* in_sizes, int n_in,
                              void* d_out, int out_size, void* d_ws, size_t ws_size,
                              hipStream_t stream) {
    const float* x    = (const float*)d_in[0];
    const int*   ei   = (const int*)d_in[1];
    const float* W1a  = (const float*)d_in[2];
    const float* b1a  = (const float*)d_in[3];
    const float* W1b  = (const float*)d_in[4];
    const float* b1b  = (const float*)d_in[5];
    const float* W2a  = (const float*)d_in[6];
    const float* b2a  = (const float*)d_in[7];
    const float* W2b  = (const float*)d_in[8];
    const float* b2b  = (const float*)d_in[9];
    const float* Wlin = (const float*)d_in[10];
    const float* blin = (const float*)d_in[11];
    float* out = (float*)d_out;

    const int N = in_sizes[0] / 64;   // 100000
    const int E = in_sizes[1] / 2;    // 1600000
    const int NBUCK = (N + BUCKET_NODES - 1) >> BUCKET_SHIFT;  // 196

    // workspace layout
    char* ws = (char*)d_ws;
    const size_t bufBytes = (size_t)N * 128 * sizeof(float);  // 51.2 MB
    float* A  = (float*)(ws + 0);
    float* B  = (float*)(ws + bufBytes);
    float* Cb = (float*)(ws + 2 * bufBytes);
    size_t off = 3 * bufBytes;
    int* row_start = (int*)(ws + off); off += ((size_t)(N + 1) * 4 + 15) & ~(size_t)15;
    int* cnt       = (int*)(ws + off); off += ((size_t)N * 4 + 15) & ~(size_t)15;
    int* partials  = (int*)(ws + off); off += 4096;
    int* gcur      = (int*)(ws + off); off += 4096;
    int* edge_src  = (int*)(ws + off); off += (size_t)E * 4;
    __half* h116   = (__half*)(ws + off); off += (size_t)N * 128 * 2;  // 25.6 MB
    // B-buffer interior aliases (B itself is never a live fp32 intermediate):
    //   [0 .. 16MB)  CSR gsrc/gdst scratch
    //   [32 .. 32.5) bf16 weights
    //   [36 .. 48.8) x fp16 shadow
    int* gsrc = (int*)B;
    int* gdst = (int*)B + (size_t)NBUCK * CAP;
    short* wHi = (short*)((char*)B + (32u << 20));
    short* wLo = wHi + 65536;
    __half* x16 = (__half*)((char*)B + (36u << 20));
    short* w1aH = wHi + 0;     short* w1aL = wLo + 0;
    short* w1bH = wHi + 8192;  short* w1bL = wLo + 8192;
    short* w2aH = wHi + 24576; short* w2aL = wLo + 24576;
    short* w2bH = wHi + 40960; short* w2bL = wLo + 40960;
    short* wlH  = wHi + 57344; short* wlL  = wLo + 57344;

    const int NB_N = (N + 255) / 256;          // 391
    const int NB_G = (N + 63) / 64;            // 1563 MLP blocks
    const int NB_S = (E + EPB - 1) / EPB;      // 391 scatter blocks
    const int NB_A128 = (N + 3) / 4;           // 25000
    const int NB_A64  = (N + 7) / 8;           // 12500
    const int NB_CVT  = (N * 64 / 2 + 255) / 256;  // 12500

    // 0. weight prep + x fp16 shadow (independent of CSR chain)
    prep_weights_kernel<<<256, 256, 0, stream>>>(W1a, W1b, W2a, W2b, Wlin, wHi, wLo);
    convert_fp16_kernel<<<NB_CVT, 256, 0, stream>>>(x, (__half2*)x16, N * 32);

    // 1. CSR build, bucket-binned
    init_gcur_kernel<<<1, 256, 0, stream>>>(gcur, NBUCK);
    bucket_scatter_kernel<<<NB_S, 256, 0, stream>>>(ei, E, gcur, gsrc, gdst, NBUCK);
    bucket_hist_kernel<<<NBUCK, 256, 0, stream>>>(gdst, gcur, cnt, N);
    scan_block_kernel<<<NB_N, 256, 0, stream>>>(cnt, row_start, partials, N);
    scan_partials_kernel<<<1, 512, 0, stream>>>(partials, NB_N);
    scan_add_kernel<<<NB_N, 256, 0, stream>>>(row_start, partials, N, E);
    bucket_fill_kernel<<<NBUCK, 256, 0, stream>>>(gsrc, gdst, gcur, row_start, edge_src, N);

    // 2. conv1: fp16-gather agg + MFMA MLP (emits fp32 + fp16 h1)
    agg64_fp16<<<NB_A64, 256, 0, stream>>>(x, (const __half2*)x16, row_start, edge_src, A, N);
    mfma_mlp_A<<<NB_G, 256, 0, stream>>>(A, w1aH, w1aL, b1a, w1bH, w1bL, b1b, Cb, h116, N);

    // 3. conv2 + head: fp16-gather agg + MFMA MLP(+head)
    agg128_fp16<<<NB_A128, 256, 0, stream>>>(Cb, (const __half2*)h116, row_start, edge_src, A, N);
    mfma_mlp_B<<<NB_G, 256, 0, stream>>>(A, w2aH, w2aL, b2a, w2bH, w2bL, b2b,
                                         wlH, wlL, blin, out, N);
}

// Round 8
// 385.324 us; speedup vs baseline: 1.5031x; 1.0416x over previous
//
#include <hip/hip_runtime.h>
#include <hip/hip_fp16.h>

// ---------------------------------------------------------------------------
// GIN (2 GINConv layers + linear head) on MI355X.
// Round 8: traffic trims.
//   - self-term reads fp16 shadow too: mlp_A no longer writes fp32 h1
//     (saves 51.2MB W + 76.8MB R across agg kernels)
//   - CSR staging packed: one dword (dst_low9<<17 | src) instead of two
//     arrays; bucket id in byte LDS sidecar for the flush
//   - agg64: fp16 self + gather (128B rows, 32-lane groups)
// MLP structure (split-bf16 MFMA, fragment-interleaved weights) unchanged.
// ---------------------------------------------------------------------------

typedef __attribute__((ext_vector_type(8))) short short8;
typedef __attribute__((ext_vector_type(4))) float f32x4;
union F8 { unsigned u[4]; short8 s; };

// pack float -> (lo bf16 << 16) | hi bf16, both RNE
__device__ inline unsigned bfpair(float v) {
    unsigned u = __float_as_uint(v);
    unsigned rh = u + 0x7fffu + ((u >> 16) & 1u);
    unsigned hf = rh & 0xffff0000u;              // hi rounded, as f32 bits
    float lof = v - __uint_as_float(hf);
    unsigned ul = __float_as_uint(lof);
    unsigned rl = ul + 0x7fffu + ((ul >> 16) & 1u);
    return (rh >> 16) | (rl & 0xffff0000u);
}

// ---------------- CSR build ----------------

constexpr int BUCKET_SHIFT = 9;
constexpr int BUCKET_NODES = 1 << BUCKET_SHIFT;
constexpr int CAP = 10240;
constexpr int EPB = 4096;
constexpr int NBUCK_MAX = 256;

__global__ __launch_bounds__(256) void init_gcur_kernel(int* __restrict__ gcur, int nbuck) {
    int i = threadIdx.x;
    if (i < nbuck) gcur[i] = i * CAP;
}

// Phase A: bin edges by dst bucket; stage packed (d9<<17|src) in LDS,
// flush contiguous runs per bucket to gpk.
__global__ __launch_bounds__(256) void bucket_scatter_kernel(const int* __restrict__ ei, int E,
                                                             int* __restrict__ gcur,
                                                             int* __restrict__ gpk,
                                                             int nbuck) {
    __shared__ int spk[EPB];
    __shared__ unsigned char sbuck[EPB];
    __shared__ int lcnt[NBUCK_MAX];
    __shared__ int lbase[NBUCK_MAX];
    __shared__ int lcur[NBUCK_MAX];
    __shared__ int gbase[NBUCK_MAX];
    __shared__ int stmp[256];

    const int t = threadIdx.x;
    const int e0 = blockIdx.x * EPB;
    const int ecnt = min(EPB, E - e0);

    for (int i = t; i < NBUCK_MAX; i += 256) lcnt[i] = 0;
    __syncthreads();

    for (int i = t; i < ecnt; i += 256) {
        int d = ei[E + e0 + i];
        atomicAdd(&lcnt[d >> BUCKET_SHIFT], 1);
    }
    __syncthreads();

    int v = lcnt[t];
    stmp[t] = v;
    __syncthreads();
    #pragma unroll
    for (int off = 1; off < 256; off <<= 1) {
        int add = (t >= off) ? stmp[t - off] : 0;
        __syncthreads();
        stmp[t] += add;
        __syncthreads();
    }
    lbase[t] = stmp[t] - v;
    lcur[t] = stmp[t] - v;
    __syncthreads();

    for (int i = t; i < ecnt; i += 256) {
        int s = ei[e0 + i];
        int d = ei[E + e0 + i];
        int b = d >> BUCKET_SHIFT;
        int p = atomicAdd(&lcur[b], 1);
        spk[p] = ((d & (BUCKET_NODES - 1)) << 17) | s;
        sbuck[p] = (unsigned char)b;
    }
    __syncthreads();

    if (t < nbuck) {
        int c = lcnt[t];
        gbase[t] = (c > 0) ? atomicAdd(&gcur[t], c) : 0;
    }
    __syncthreads();

    for (int i = t; i < ecnt; i += 256) {
        int b = sbuck[i];
        int gp = gbase[b] + (i - lbase[b]);
        if (gp < (b + 1) * CAP) gpk[gp] = spk[i];
    }
}

// Phase H: per-node histogram via LDS atomics (bucket-local)
__global__ __launch_bounds__(256) void bucket_hist_kernel(const int* __restrict__ gpk,
                                                          const int* __restrict__ gcur,
                                                          int* __restrict__ cnt, int N) {
    __shared__ int h[BUCKET_NODES];
    const int t = threadIdx.x;
    const int b = blockIdx.x;
    const int base = b << BUCKET_SHIFT;
    for (int i = t; i < BUCKET_NODES; i += 256) h[i] = 0;
    __syncthreads();
    int cb = min(gcur[b] - b * CAP, CAP);
    const int* pp = gpk + (size_t)b * CAP;
    for (int i = t; i < cb; i += 256) atomicAdd(&h[((unsigned)pp[i]) >> 17], 1);
    __syncthreads();
    for (int i = t; i < BUCKET_NODES && base + i < N; i += 256) cnt[base + i] = h[i];
}

__global__ __launch_bounds__(256) void scan_block_kernel(const int* __restrict__ cnt,
                                                         int* __restrict__ rs,
                                                         int* __restrict__ partials,
                                                         int N) {
    __shared__ int s[256];
    int t = threadIdx.x;
    int i = blockIdx.x * 256 + t;
    int v = (i < N) ? cnt[i] : 0;
    s[t] = v;
    __syncthreads();
    #pragma unroll
    for (int off = 1; off < 256; off <<= 1) {
        int add = (t >= off) ? s[t - off] : 0;
        __syncthreads();
        s[t] += add;
        __syncthreads();
    }
    if (i < N) rs[i] = s[t] - v;
    if (t == 255) partials[blockIdx.x] = s[255];
}

__global__ __launch_bounds__(512) void scan_partials_kernel(int* __restrict__ partials,
                                                            int nb) {
    __shared__ int s[512];
    int t = threadIdx.x;
    int v = (t < nb) ? partials[t] : 0;
    s[t] = v;
    __syncthreads();
    #pragma unroll
    for (int off = 1; off < 512; off <<= 1) {
        int add = (t >= off) ? s[t - off] : 0;
        __syncthreads();
        s[t] += add;
        __syncthreads();
    }
    if (t < nb) partials[t] = s[t] - v;
}

__global__ __launch_bounds__(256) void scan_add_kernel(int* __restrict__ rs,
                                                       const int* __restrict__ partials,
                                                       int N, int E) {
    int i = blockIdx.x * 256 + threadIdx.x;
    if (i < N) rs[i] += partials[blockIdx.x];
    if (i == 0) rs[N] = E;
}

// Phase B: exact CSR fill with LDS cursors
__global__ __launch_bounds__(256) void bucket_fill_kernel(const int* __restrict__ gpk,
                                                          const int* __restrict__ gcur,
                                                          const int* __restrict__ rs,
                                                          int* __restrict__ edge_src, int N) {
    __shared__ int cur[BUCKET_NODES];
    const int t = threadIdx.x;
    const int b = blockIdx.x;
    const int base = b << BUCKET_SHIFT;
    for (int i = t; i < BUCKET_NODES; i += 256) cur[i] = rs[min(base + i, N)];
    __syncthreads();
    int cb = min(gcur[b] - b * CAP, CAP);
    const int* pp = gpk + (size_t)b * CAP;
    for (int i = t; i < cb; i += 256) {
        unsigned pw = (unsigned)pp[i];
        int p = atomicAdd(&cur[pw >> 17], 1);
        edge_src[p] = (int)(pw & 0x1FFFFu);
    }
}

// ---------------- fp16 convert + aggregation ----------------

__global__ __launch_bounds__(256) void convert_fp16_kernel(const float* __restrict__ src,
                                                           __half2* __restrict__ dst, int n2) {
    int i = blockIdx.x * 256 + threadIdx.x;
    if (i < n2) {
        float2 v = reinterpret_cast<const float2*>(src)[i];
        dst[i] = __floats2half2_rn(v.x, v.y);
    }
}

// Z[i] = fp16(H[i]) + sum_j fp16(H[src_j]);  D=128, one wave per node,
// lane l covers cols (2l, 2l+1) via one dword per edge.
__global__ __launch_bounds__(256) void agg128_fp16(const __half2* __restrict__ H16,
                                                   const int* __restrict__ row_start,
                                                   const int* __restrict__ edge_src,
                                                   float* __restrict__ Z, int N) {
    int wave = threadIdx.x >> 6, lane = threadIdx.x & 63;
    int node = blockIdx.x * 4 + wave;
    if (node >= N) return;
    int beg = row_start[node], end = row_start[node + 1];
    float2 self = __half22float2(H16[(size_t)node * 64 + lane]);
    float a0 = self.x, a1 = self.y;
    int i = beg;
    for (; i + 4 <= end; i += 4) {
        int s0 = edge_src[i], s1 = edge_src[i + 1];
        int s2 = edge_src[i + 2], s3 = edge_src[i + 3];
        float2 v0 = __half22float2(H16[(size_t)s0 * 64 + lane]);
        float2 v1 = __half22float2(H16[(size_t)s1 * 64 + lane]);
        float2 v2 = __half22float2(H16[(size_t)s2 * 64 + lane]);
        float2 v3 = __half22float2(H16[(size_t)s3 * 64 + lane]);
        a0 += (v0.x + v1.x) + (v2.x + v3.x);
        a1 += (v0.y + v1.y) + (v2.y + v3.y);
    }
    for (; i < end; ++i) {
        float2 v = __half22float2(H16[(size_t)edge_src[i] * 64 + lane]);
        a0 += v.x;
        a1 += v.y;
    }
    float2 o; o.x = a0; o.y = a1;
    reinterpret_cast<float2*>(Z + (size_t)node * 128)[lane] = o;
}

// D=64: two nodes per wave (32-lane groups, 128B coalesced gathers), fp16 self.
__global__ __launch_bounds__(256) void agg64_fp16(const __half2* __restrict__ H16,
                                                  const int* __restrict__ row_start,
                                                  const int* __restrict__ edge_src,
                                                  float* __restrict__ Z, int N) {
    int t = threadIdx.x;
    int grp = t >> 5;          // 0..7
    int gl = t & 31;
    int node = blockIdx.x * 8 + grp;
    if (node >= N) return;
    int beg = row_start[node], end = row_start[node + 1];
    float2 self = __half22float2(H16[(size_t)node * 32 + gl]);
    float a0 = self.x, a1 = self.y;
    int i = beg;
    for (; i + 4 <= end; i += 4) {
        int s0 = edge_src[i], s1 = edge_src[i + 1];
        int s2 = edge_src[i + 2], s3 = edge_src[i + 3];
        float2 v0 = __half22float2(H16[(size_t)s0 * 32 + gl]);
        float2 v1 = __half22float2(H16[(size_t)s1 * 32 + gl]);
        float2 v2 = __half22float2(H16[(size_t)s2 * 32 + gl]);
        float2 v3 = __half22float2(H16[(size_t)s3 * 32 + gl]);
        a0 += (v0.x + v1.x) + (v2.x + v3.x);
        a1 += (v0.y + v1.y) + (v2.y + v3.y);
    }
    for (; i < end; ++i) {
        float2 v = __half22float2(H16[(size_t)edge_src[i] * 32 + gl]);
        a0 += v.x;
        a1 += v.y;
    }
    float2 o; o.x = a0; o.y = a1;
    reinterpret_cast<float2*>(Z + (size_t)node * 64)[gl] = o;
}

// ---------------- weight prep: fragment-interleaved bf16 hi/lo --------------

__global__ __launch_bounds__(256) void prep_weights_kernel(const float* __restrict__ W1a,
                                                           const float* __restrict__ W1b,
                                                           const float* __restrict__ W2a,
                                                           const float* __restrict__ W2b,
                                                           const float* __restrict__ Wlin,
                                                           short* __restrict__ hi,
                                                           short* __restrict__ lo) {
    int i = blockIdx.x * 256 + threadIdx.x;   // 0..65535
    const float* W;
    int base, K, N;
    if (i < 8192)       { W = W1a;  base = 0;     K = 64;  N = 128; }
    else if (i < 24576) { W = W1b;  base = 8192;  K = 128; N = 128; }
    else if (i < 40960) { W = W2a;  base = 24576; K = 128; N = 128; }
    else if (i < 57344) { W = W2b;  base = 40960; K = 128; N = 128; }
    else                { W = Wlin; base = 57344; K = 128; N = 64;  }
    int rel = i - base;
    int NT = N >> 4;
    int j  = rel & 7;
    int l  = (rel >> 3) & 63;
    int tc = rel >> 9;            // c*NT + nt
    int nt = tc % NT;
    int c  = tc / NT;
    int n  = nt * 16 + (l & 15);
    int k  = c * 32 + ((l >> 4) << 3) + j;
    float v = W[k * N + n];
    unsigned p = bfpair(v);
    hi[i] = (short)(p & 0xffffu);
    lo[i] = (short)(p >> 16);
}

// ---------------- MFMA fused MLP --------------------------------------------

template <int K>
__device__ inline void stage_global(const float* __restrict__ z, int M, int m0,
                                    unsigned* __restrict__ P, int t) {
    constexpr int KC = K / 32;
    constexpr int NF = 4 * KC * 64;
    #pragma unroll
    for (int fi = t; fi < NF; fi += 256) {
        int l = fi & 63;
        int tc = fi >> 6;
        int c = tc & (KC - 1);
        int T = tc / KC;
        int row = m0 + T * 16 + (l & 15);
        if (row >= M) row = M - 1;
        int kb = c * 32 + ((l >> 4) << 3);
        const float* p = z + (size_t)row * K + kb;
        float4 v0 = *reinterpret_cast<const float4*>(p);
        float4 v1 = *reinterpret_cast<const float4*>(p + 4);
        int base = ((T * KC + c) * 8) * 66 + l;
        P[base + 0 * 66] = bfpair(v0.x);
        P[base + 1 * 66] = bfpair(v0.y);
        P[base + 2 * 66] = bfpair(v0.z);
        P[base + 3 * 66] = bfpair(v0.w);
        P[base + 4 * 66] = bfpair(v1.x);
        P[base + 5 * 66] = bfpair(v1.y);
        P[base + 6 * 66] = bfpair(v1.z);
        P[base + 7 * 66] = bfpair(v1.w);
    }
}

template <int K, int NT>
__device__ inline void stage_compute(const unsigned* __restrict__ P,
                                     const short* __restrict__ WH,
                                     const short* __restrict__ WL,
                                     int w, int lane, f32x4* acc) {
    constexpr int KC = K / 32;
    const unsigned* Pbase = P + (w * KC * 8) * 66 + lane;
    const short8* bhp = reinterpret_cast<const short8*>(WH) + lane;
    const short8* blp = reinterpret_cast<const short8*>(WL) + lane;
    for (int c = 0; c < KC; ++c) {
        unsigned d[8];
        #pragma unroll
        for (int j = 0; j < 8; ++j) d[j] = Pbase[(c * 8 + j) * 66];
        F8 ah, al;
        #pragma unroll
        for (int j = 0; j < 4; ++j) {
            ah.u[j] = __builtin_amdgcn_perm(d[2 * j + 1], d[2 * j], 0x05040100u);
            al.u[j] = __builtin_amdgcn_perm(d[2 * j + 1], d[2 * j], 0x07060302u);
        }
        F8 bh[NT], bl[NT];
        #pragma unroll
        for (int nt = 0; nt < NT; ++nt) {
            bh[nt].s = bhp[(c * NT + nt) * 64];
            bl[nt].s = blp[(c * NT + nt) * 64];
        }
        #pragma unroll
        for (int nt = 0; nt < NT; ++nt) {
            acc[nt] = __builtin_amdgcn_mfma_f32_16x16x32_bf16(ah.s, bh[nt].s, acc[nt], 0, 0, 0);
            acc[nt] = __builtin_amdgcn_mfma_f32_16x16x32_bf16(al.s, bh[nt].s, acc[nt], 0, 0, 0);
            acc[nt] = __builtin_amdgcn_mfma_f32_16x16x32_bf16(ah.s, bl[nt].s, acc[nt], 0, 0, 0);
        }
    }
}

__device__ inline void epilogue_lds(const f32x4* acc, const float* __restrict__ bias,
                                    unsigned* __restrict__ Pout, int w, int lane) {
    int q = lane >> 4, ln = lane & 15;
    #pragma unroll
    for (int nt = 0; nt < 8; ++nt) {
        int col = nt * 16 + ln;
        float b = bias[col];
        int c = col >> 5, jj = col & 7, q2 = (col >> 3) & 3;
        int pb = ((w * 4 + c) * 8 + jj) * 66;
        #pragma unroll
        for (int r = 0; r < 4; ++r) {
            float v = fmaxf(acc[nt][r] + b, 0.f);
            Pout[pb + ((q * 4 + r) | (q2 << 4))] = bfpair(v);
        }
    }
}

// conv1 MLP: z[M,64] -> relu(relu(z@Wa+ba)@Wb+bb) = h1 (fp16 only)
__global__ __launch_bounds__(256, 2) void mfma_mlp_A(const float* __restrict__ z,
                                                     const short* __restrict__ WaH,
                                                     const short* __restrict__ WaL,
                                                     const float* __restrict__ ba,
                                                     const short* __restrict__ WbH,
                                                     const short* __restrict__ WbL,
                                                     const float* __restrict__ bb,
                                                     __half* __restrict__ H16out, int M) {
    __shared__ unsigned P[4 * 4 * 8 * 66];   // 33792 B, single buffer
    const int t = threadIdx.x;
    const int w = t >> 6, lane = t & 63;
    const int m0 = blockIdx.x * 64;
    const int q = lane >> 4, ln = lane & 15;

    stage_global<64>(z, M, m0, P, t);
    __syncthreads();

    f32x4 acc[8];
    #pragma unroll
    for (int i = 0; i < 8; ++i) acc[i] = (f32x4){0.f, 0.f, 0.f, 0.f};
    stage_compute<64, 8>(P, WaH, WaL, w, lane, acc);
    __syncthreads();
    epilogue_lds(acc, ba, P, w, lane);
    __syncthreads();

    #pragma unroll
    for (int i = 0; i < 8; ++i) acc[i] = (f32x4){0.f, 0.f, 0.f, 0.f};
    stage_compute<128, 8>(P, WbH, WbL, w, lane, acc);

    #pragma unroll
    for (int nt = 0; nt < 8; ++nt) {
        int col = nt * 16 + ln;
        float b = bb[col];
        #pragma unroll
        for (int r = 0; r < 4; ++r) {
            int row = m0 + w * 16 + q * 4 + r;
            if (row < M) {
                float v = fmaxf(acc[nt][r] + b, 0.f);
                H16out[(size_t)row * 128 + col] = __float2half_rn(v);
            }
        }
    }
}

// conv2 MLP + head
__global__ __launch_bounds__(256, 2) void mfma_mlp_B(const float* __restrict__ z,
                                                     const short* __restrict__ WaH,
                                                     const short* __restrict__ WaL,
                                                     const float* __restrict__ ba,
                                                     const short* __restrict__ WbH,
                                                     const short* __restrict__ WbL,
                                                     const float* __restrict__ bb,
                                                     const short* __restrict__ WlH,
                                                     const short* __restrict__ WlL,
                                                     const float* __restrict__ bl,
                                                     float* __restrict__ Out, int M) {
    __shared__ unsigned P[4 * 4 * 8 * 66];   // 33792 B, single buffer
    const int t = threadIdx.x;
    const int w = t >> 6, lane = t & 63;
    const int m0 = blockIdx.x * 64;
    const int q = lane >> 4, ln = lane & 15;

    stage_global<128>(z, M, m0, P, t);
    __syncthreads();

    f32x4 acc[8];
    #pragma unroll
    for (int i = 0; i < 8; ++i) acc[i] = (f32x4){0.f, 0.f, 0.f, 0.f};
    stage_compute<128, 8>(P, WaH, WaL, w, lane, acc);
    __syncthreads();
    epilogue_lds(acc, ba, P, w, lane);
    __syncthreads();

    #pragma unroll
    for (int i = 0; i < 8; ++i) acc[i] = (f32x4){0.f, 0.f, 0.f, 0.f};
    stage_compute<128, 8>(P, WbH, WbL, w, lane, acc);
    __syncthreads();
    epilogue_lds(acc, bb, P, w, lane);
    __syncthreads();

    f32x4 accC[4];
    #pragma unroll
    for (int i = 0; i < 4; ++i) accC[i] = (f32x4){0.f, 0.f, 0.f, 0.f};
    stage_compute<128, 4>(P, WlH, WlL, w, lane, accC);

    #pragma unroll
    for (int nt = 0; nt < 4; ++nt) {
        int col = nt * 16 + ln;
        float b = bl[col];
        #pragma unroll
        for (int r = 0; r < 4; ++r) {
            int row = m0 + w * 16 + q * 4 + r;
            if (row < M) Out[(size_t)row * 64 + col] = accC[nt][r] + b;
        }
    }
}

// ---------------------------------------------------------------------------

extern "C" void kernel_launch(void* const* d_in, const int* in_sizes, int n_in,
                              void* d_out, int out_size, void* d_ws, size_t ws_size,
                              hipStream_t stream) {
    const float* x    = (const float*)d_in[0];
    const int*   ei   = (const int*)d_in[1];
    const float* W1a  = (const float*)d_in[2];
    const float* b1a  = (const float*)d_in[3];
    const float* W1b  = (const float*)d_in[4];
    const float* b1b  = (const float*)d_in[5];
    const float* W2a  = (const float*)d_in[6];
    const float* b2a  = (const float*)d_in[7];
    const float* W2b  = (const float*)d_in[8];
    const float* b2b  = (const float*)d_in[9];
    const float* Wlin = (const float*)d_in[10];
    const float* blin = (const float*)d_in[11];
    float* out = (float*)d_out;

    const int N = in_sizes[0] / 64;   // 100000
    const int E = in_sizes[1] / 2;    // 1600000
    const int NBUCK = (N + BUCKET_NODES - 1) >> BUCKET_SHIFT;  // 196

    // workspace layout
    char* ws = (char*)d_ws;
    const size_t bufBytes = (size_t)N * 128 * sizeof(float);  // 51.2 MB
    float* A  = (float*)(ws + 0);
    float* B  = (float*)(ws + bufBytes);
    size_t off = 3 * bufBytes;
    int* row_start = (int*)(ws + off); off += ((size_t)(N + 1) * 4 + 15) & ~(size_t)15;
    int* cnt       = (int*)(ws + off); off += ((size_t)N * 4 + 15) & ~(size_t)15;
    int* partials  = (int*)(ws + off); off += 4096;
    int* gcur      = (int*)(ws + off); off += 4096;
    int* edge_src  = (int*)(ws + off); off += (size_t)E * 4;
    __half* h116   = (__half*)(ws + off); off += (size_t)N * 128 * 2;  // 25.6 MB
    // B-buffer interior aliases:
    //   [0 .. 8MB)   CSR gpk scratch
    //   [32 .. 32.5) bf16 weights
    //   [36 .. 48.8) x fp16 shadow
    int* gpk = (int*)B;
    short* wHi = (short*)((char*)B + (32u << 20));
    short* wLo = wHi + 65536;
    __half* x16 = (__half*)((char*)B + (36u << 20));
    short* w1aH = wHi + 0;     short* w1aL = wLo + 0;
    short* w1bH = wHi + 8192;  short* w1bL = wLo + 8192;
    short* w2aH = wHi + 24576; short* w2aL = wLo + 24576;
    short* w2bH = wHi + 40960; short* w2bL = wLo + 40960;
    short* wlH  = wHi + 57344; short* wlL  = wLo + 57344;

    const int NB_N = (N + 255) / 256;          // 391
    const int NB_G = (N + 63) / 64;            // 1563 MLP blocks
    const int NB_S = (E + EPB - 1) / EPB;      // 391 scatter blocks
    const int NB_A128 = (N + 3) / 4;           // 25000
    const int NB_A64  = (N + 7) / 8;           // 12500
    const int NB_CVT  = (N * 64 / 2 + 255) / 256;  // 12500

    // 0. weight prep + x fp16 shadow (independent of CSR chain)
    prep_weights_kernel<<<256, 256, 0, stream>>>(W1a, W1b, W2a, W2b, Wlin, wHi, wLo);
    convert_fp16_kernel<<<NB_CVT, 256, 0, stream>>>(x, (__half2*)x16, N * 32);

    // 1. CSR build, bucket-binned, packed staging
    init_gcur_kernel<<<1, 256, 0, stream>>>(gcur, NBUCK);
    bucket_scatter_kernel<<<NB_S, 256, 0, stream>>>(ei, E, gcur, gpk, NBUCK);
    bucket_hist_kernel<<<NBUCK, 256, 0, stream>>>(gpk, gcur, cnt, N);
    scan_block_kernel<<<NB_N, 256, 0, stream>>>(cnt, row_start, partials, N);
    scan_partials_kernel<<<1, 512, 0, stream>>>(partials, NB_N);
    scan_add_kernel<<<NB_N, 256, 0, stream>>>(row_start, partials, N, E);
    bucket_fill_kernel<<<NBUCK, 256, 0, stream>>>(gpk, gcur, row_start, edge_src, N);

    // 2. conv1: fp16 agg + MFMA MLP (emits fp16 h1 only)
    agg64_fp16<<<NB_A64, 256, 0, stream>>>((const __half2*)x16, row_start, edge_src, A, N);
    mfma_mlp_A<<<NB_G, 256, 0, stream>>>(A, w1aH, w1aL, b1a, w1bH, w1bL, b1b, h116, N);

    // 3. conv2 + head: fp16 agg + MFMA MLP(+head)
    agg128_fp16<<<NB_A128, 256, 0, stream>>>((const __half2*)h116, row_start, edge_src, A, N);
    mfma_mlp_B<<<NB_G, 256, 0, stream>>>(A, w2aH, w2aL, b2a, w2bH, w2bL, b2b,
                                         wlH, wlL, blin, out, N);
}

// Round 9
// 367.766 us; speedup vs baseline: 1.5749x; 1.0477x over previous
//
#include <hip/hip_runtime.h>
#include <hip/hip_fp16.h>

// ---------------------------------------------------------------------------
// GIN (2 GINConv layers + linear head) on MI355X.
// Round 9:
//   - z (agg output) stored fp16: halves agg write + MLP staging read
//   - MLP blocks cover 128 rows (2 m-tiles per wave): B-fragment L2 traffic
//     and block count halved; LDS 67.6KB, 2 blocks/CU
// CSR build, fp16 gather agg, split-bf16 MFMA + fragment-interleaved weights
// unchanged in structure.
// ---------------------------------------------------------------------------

typedef __attribute__((ext_vector_type(8))) short short8;
typedef __attribute__((ext_vector_type(4))) float f32x4;
union F8 { unsigned u[4]; short8 s; };

// pack float -> (lo bf16 << 16) | hi bf16, both RNE
__device__ inline unsigned bfpair(float v) {
    unsigned u = __float_as_uint(v);
    unsigned rh = u + 0x7fffu + ((u >> 16) & 1u);
    unsigned hf = rh & 0xffff0000u;              // hi rounded, as f32 bits
    float lof = v - __uint_as_float(hf);
    unsigned ul = __float_as_uint(lof);
    unsigned rl = ul + 0x7fffu + ((ul >> 16) & 1u);
    return (rh >> 16) | (rl & 0xffff0000u);
}

// ---------------- CSR build (unchanged from R8) ----------------

constexpr int BUCKET_SHIFT = 9;
constexpr int BUCKET_NODES = 1 << BUCKET_SHIFT;
constexpr int CAP = 10240;
constexpr int EPB = 4096;
constexpr int NBUCK_MAX = 256;

__global__ __launch_bounds__(256) void init_gcur_kernel(int* __restrict__ gcur, int nbuck) {
    int i = threadIdx.x;
    if (i < nbuck) gcur[i] = i * CAP;
}

__global__ __launch_bounds__(256) void bucket_scatter_kernel(const int* __restrict__ ei, int E,
                                                             int* __restrict__ gcur,
                                                             int* __restrict__ gpk,
                                                             int nbuck) {
    __shared__ int spk[EPB];
    __shared__ unsigned char sbuck[EPB];
    __shared__ int lcnt[NBUCK_MAX];
    __shared__ int lbase[NBUCK_MAX];
    __shared__ int lcur[NBUCK_MAX];
    __shared__ int gbase[NBUCK_MAX];
    __shared__ int stmp[256];

    const int t = threadIdx.x;
    const int e0 = blockIdx.x * EPB;
    const int ecnt = min(EPB, E - e0);

    for (int i = t; i < NBUCK_MAX; i += 256) lcnt[i] = 0;
    __syncthreads();

    for (int i = t; i < ecnt; i += 256) {
        int d = ei[E + e0 + i];
        atomicAdd(&lcnt[d >> BUCKET_SHIFT], 1);
    }
    __syncthreads();

    int v = lcnt[t];
    stmp[t] = v;
    __syncthreads();
    #pragma unroll
    for (int off = 1; off < 256; off <<= 1) {
        int add = (t >= off) ? stmp[t - off] : 0;
        __syncthreads();
        stmp[t] += add;
        __syncthreads();
    }
    lbase[t] = stmp[t] - v;
    lcur[t] = stmp[t] - v;
    __syncthreads();

    for (int i = t; i < ecnt; i += 256) {
        int s = ei[e0 + i];
        int d = ei[E + e0 + i];
        int b = d >> BUCKET_SHIFT;
        int p = atomicAdd(&lcur[b], 1);
        spk[p] = ((d & (BUCKET_NODES - 1)) << 17) | s;
        sbuck[p] = (unsigned char)b;
    }
    __syncthreads();

    if (t < nbuck) {
        int c = lcnt[t];
        gbase[t] = (c > 0) ? atomicAdd(&gcur[t], c) : 0;
    }
    __syncthreads();

    for (int i = t; i < ecnt; i += 256) {
        int b = sbuck[i];
        int gp = gbase[b] + (i - lbase[b]);
        if (gp < (b + 1) * CAP) gpk[gp] = spk[i];
    }
}

__global__ __launch_bounds__(256) void bucket_hist_kernel(const int* __restrict__ gpk,
                                                          const int* __restrict__ gcur,
                                                          int* __restrict__ cnt, int N) {
    __shared__ int h[BUCKET_NODES];
    const int t = threadIdx.x;
    const int b = blockIdx.x;
    const int base = b << BUCKET_SHIFT;
    for (int i = t; i < BUCKET_NODES; i += 256) h[i] = 0;
    __syncthreads();
    int cb = min(gcur[b] - b * CAP, CAP);
    const int* pp = gpk + (size_t)b * CAP;
    for (int i = t; i < cb; i += 256) atomicAdd(&h[((unsigned)pp[i]) >> 17], 1);
    __syncthreads();
    for (int i = t; i < BUCKET_NODES && base + i < N; i += 256) cnt[base + i] = h[i];
}

__global__ __launch_bounds__(256) void scan_block_kernel(const int* __restrict__ cnt,
                                                         int* __restrict__ rs,
                                                         int* __restrict__ partials,
                                                         int N) {
    __shared__ int s[256];
    int t = threadIdx.x;
    int i = blockIdx.x * 256 + t;
    int v = (i < N) ? cnt[i] : 0;
    s[t] = v;
    __syncthreads();
    #pragma unroll
    for (int off = 1; off < 256; off <<= 1) {
        int add = (t >= off) ? s[t - off] : 0;
        __syncthreads();
        s[t] += add;
        __syncthreads();
    }
    if (i < N) rs[i] = s[t] - v;
    if (t == 255) partials[blockIdx.x] = s[255];
}

__global__ __launch_bounds__(512) void scan_partials_kernel(int* __restrict__ partials,
                                                            int nb) {
    __shared__ int s[512];
    int t = threadIdx.x;
    int v = (t < nb) ? partials[t] : 0;
    s[t] = v;
    __syncthreads();
    #pragma unroll
    for (int off = 1; off < 512; off <<= 1) {
        int add = (t >= off) ? s[t - off] : 0;
        __syncthreads();
        s[t] += add;
        __syncthreads();
    }
    if (t < nb) partials[t] = s[t] - v;
}

__global__ __launch_bounds__(256) void scan_add_kernel(int* __restrict__ rs,
                                                       const int* __restrict__ partials,
                                                       int N, int E) {
    int i = blockIdx.x * 256 + threadIdx.x;
    if (i < N) rs[i] += partials[blockIdx.x];
    if (i == 0) rs[N] = E;
}

__global__ __launch_bounds__(256) void bucket_fill_kernel(const int* __restrict__ gpk,
                                                          const int* __restrict__ gcur,
                                                          const int* __restrict__ rs,
                                                          int* __restrict__ edge_src, int N) {
    __shared__ int cur[BUCKET_NODES];
    const int t = threadIdx.x;
    const int b = blockIdx.x;
    const int base = b << BUCKET_SHIFT;
    for (int i = t; i < BUCKET_NODES; i += 256) cur[i] = rs[min(base + i, N)];
    __syncthreads();
    int cb = min(gcur[b] - b * CAP, CAP);
    const int* pp = gpk + (size_t)b * CAP;
    for (int i = t; i < cb; i += 256) {
        unsigned pw = (unsigned)pp[i];
        int p = atomicAdd(&cur[pw >> 17], 1);
        edge_src[p] = (int)(pw & 0x1FFFFu);
    }
}

// ---------------- fp16 convert + aggregation (fp16 out) ----------------

__global__ __launch_bounds__(256) void convert_fp16_kernel(const float* __restrict__ src,
                                                           __half2* __restrict__ dst, int n2) {
    int i = blockIdx.x * 256 + threadIdx.x;
    if (i < n2) {
        float2 v = reinterpret_cast<const float2*>(src)[i];
        dst[i] = __floats2half2_rn(v.x, v.y);
    }
}

// Z16[i] = fp16( fp16(H[i]) + sum_j fp16(H[src_j]) );  D=128, one wave/node.
__global__ __launch_bounds__(256) void agg128_fp16(const __half2* __restrict__ H16,
                                                   const int* __restrict__ row_start,
                                                   const int* __restrict__ edge_src,
                                                   __half2* __restrict__ Z16, int N) {
    int wave = threadIdx.x >> 6, lane = threadIdx.x & 63;
    int node = blockIdx.x * 4 + wave;
    if (node >= N) return;
    int beg = row_start[node], end = row_start[node + 1];
    float2 self = __half22float2(H16[(size_t)node * 64 + lane]);
    float a0 = self.x, a1 = self.y;
    int i = beg;
    for (; i + 4 <= end; i += 4) {
        int s0 = edge_src[i], s1 = edge_src[i + 1];
        int s2 = edge_src[i + 2], s3 = edge_src[i + 3];
        float2 v0 = __half22float2(H16[(size_t)s0 * 64 + lane]);
        float2 v1 = __half22float2(H16[(size_t)s1 * 64 + lane]);
        float2 v2 = __half22float2(H16[(size_t)s2 * 64 + lane]);
        float2 v3 = __half22float2(H16[(size_t)s3 * 64 + lane]);
        a0 += (v0.x + v1.x) + (v2.x + v3.x);
        a1 += (v0.y + v1.y) + (v2.y + v3.y);
    }
    for (; i < end; ++i) {
        float2 v = __half22float2(H16[(size_t)edge_src[i] * 64 + lane]);
        a0 += v.x;
        a1 += v.y;
    }
    Z16[(size_t)node * 64 + lane] = __floats2half2_rn(a0, a1);
}

// D=64: two nodes per wave (32-lane groups, 128B coalesced gathers).
__global__ __launch_bounds__(256) void agg64_fp16(const __half2* __restrict__ H16,
                                                  const int* __restrict__ row_start,
                                                  const int* __restrict__ edge_src,
                                                  __half2* __restrict__ Z16, int N) {
    int t = threadIdx.x;
    int grp = t >> 5;          // 0..7
    int gl = t & 31;
    int node = blockIdx.x * 8 + grp;
    if (node >= N) return;
    int beg = row_start[node], end = row_start[node + 1];
    float2 self = __half22float2(H16[(size_t)node * 32 + gl]);
    float a0 = self.x, a1 = self.y;
    int i = beg;
    for (; i + 4 <= end; i += 4) {
        int s0 = edge_src[i], s1 = edge_src[i + 1];
        int s2 = edge_src[i + 2], s3 = edge_src[i + 3];
        float2 v0 = __half22float2(H16[(size_t)s0 * 32 + gl]);
        float2 v1 = __half22float2(H16[(size_t)s1 * 32 + gl]);
        float2 v2 = __half22float2(H16[(size_t)s2 * 32 + gl]);
        float2 v3 = __half22float2(H16[(size_t)s3 * 32 + gl]);
        a0 += (v0.x + v1.x) + (v2.x + v3.x);
        a1 += (v0.y + v1.y) + (v2.y + v3.y);
    }
    for (; i < end; ++i) {
        float2 v = __half22float2(H16[(size_t)edge_src[i] * 32 + gl]);
        a0 += v.x;
        a1 += v.y;
    }
    Z16[(size_t)node * 32 + gl] = __floats2half2_rn(a0, a1);
}

// ---------------- weight prep: fragment-interleaved bf16 hi/lo --------------

__global__ __launch_bounds__(256) void prep_weights_kernel(const float* __restrict__ W1a,
                                                           const float* __restrict__ W1b,
                                                           const float* __restrict__ W2a,
                                                           const float* __restrict__ W2b,
                                                           const float* __restrict__ Wlin,
                                                           short* __restrict__ hi,
                                                           short* __restrict__ lo) {
    int i = blockIdx.x * 256 + threadIdx.x;   // 0..65535
    const float* W;
    int base, K, N;
    if (i < 8192)       { W = W1a;  base = 0;     K = 64;  N = 128; }
    else if (i < 24576) { W = W1b;  base = 8192;  K = 128; N = 128; }
    else if (i < 40960) { W = W2a;  base = 24576; K = 128; N = 128; }
    else if (i < 57344) { W = W2b;  base = 40960; K = 128; N = 128; }
    else                { W = Wlin; base = 57344; K = 128; N = 64;  }
    int rel = i - base;
    int NT = N >> 4;
    int j  = rel & 7;
    int l  = (rel >> 3) & 63;
    int tc = rel >> 9;            // c*NT + nt
    int nt = tc % NT;
    int c  = tc / NT;
    int n  = nt * 16 + (l & 15);
    int k  = c * 32 + ((l >> 4) << 3) + j;
    float v = W[k * N + n];
    unsigned p = bfpair(v);
    hi[i] = (short)(p & 0xffffu);
    lo[i] = (short)(p >> 16);
}

// ---------------- MFMA fused MLP (128 rows/block, 2 m-tiles/wave) -----------
// LDS A-tile layout: dword ((T*KC + c)*8 + j)*66 + l holds (lo<<16)|hi of
// A[T*16 + (l&15)][c*32 + (l>>4)*8 + j], T in 0..7.

template <int K>
__device__ inline void stage_global16(const __half2* __restrict__ z, int M, int m0,
                                      unsigned* __restrict__ P, int t) {
    constexpr int KC = K / 32;
    constexpr int NF = 8 * KC * 64;
    #pragma unroll
    for (int fi = t; fi < NF; fi += 256) {
        int l = fi & 63;
        int tc = fi >> 6;
        int c = tc & (KC - 1);
        int T = tc / KC;
        int row = m0 + T * 16 + (l & 15);
        if (row >= M) row = M - 1;
        int kb = c * 32 + ((l >> 4) << 3);   // multiple of 8
        const __half2* p = z + (size_t)row * (K / 2) + (kb >> 1);
        uint4 v = *reinterpret_cast<const uint4*>(p);  // 8 halves
        float2 f0 = __half22float2(*reinterpret_cast<__half2*>(&v.x));
        float2 f1 = __half22float2(*reinterpret_cast<__half2*>(&v.y));
        float2 f2 = __half22float2(*reinterpret_cast<__half2*>(&v.z));
        float2 f3 = __half22float2(*reinterpret_cast<__half2*>(&v.w));
        int base = ((T * KC + c) * 8) * 66 + l;
        P[base + 0 * 66] = bfpair(f0.x);
        P[base + 1 * 66] = bfpair(f0.y);
        P[base + 2 * 66] = bfpair(f1.x);
        P[base + 3 * 66] = bfpair(f1.y);
        P[base + 4 * 66] = bfpair(f2.x);
        P[base + 5 * 66] = bfpair(f2.y);
        P[base + 6 * 66] = bfpair(f3.x);
        P[base + 7 * 66] = bfpair(f3.y);
    }
}

// B-frags loaded once per k-chunk, shared across the wave's 2 m-tiles.
template <int K, int NT>
__device__ inline void stage_compute(const unsigned* __restrict__ P,
                                     const short* __restrict__ WH,
                                     const short* __restrict__ WL,
                                     int w, int lane, f32x4 (*acc)[8]) {
    constexpr int KC = K / 32;
    const short8* bhp = reinterpret_cast<const short8*>(WH) + lane;
    const short8* blp = reinterpret_cast<const short8*>(WL) + lane;
    for (int c = 0; c < KC; ++c) {
        F8 bh[NT], bl[NT];
        #pragma unroll
        for (int nt = 0; nt < NT; ++nt) {
            bh[nt].s = bhp[(c * NT + nt) * 64];
            bl[nt].s = blp[(c * NT + nt) * 64];
        }
        #pragma unroll
        for (int mt = 0; mt < 2; ++mt) {
            const int T = w * 2 + mt;
            const unsigned* Pb = P + ((T * KC + c) * 8) * 66 + lane;
            unsigned d[8];
            #pragma unroll
            for (int j = 0; j < 8; ++j) d[j] = Pb[j * 66];
            F8 ah, al;
            #pragma unroll
            for (int j = 0; j < 4; ++j) {
                ah.u[j] = __builtin_amdgcn_perm(d[2 * j + 1], d[2 * j], 0x05040100u);
                al.u[j] = __builtin_amdgcn_perm(d[2 * j + 1], d[2 * j], 0x07060302u);
            }
            #pragma unroll
            for (int nt = 0; nt < NT; ++nt) {
                acc[mt][nt] = __builtin_amdgcn_mfma_f32_16x16x32_bf16(ah.s, bh[nt].s, acc[mt][nt], 0, 0, 0);
                acc[mt][nt] = __builtin_amdgcn_mfma_f32_16x16x32_bf16(al.s, bh[nt].s, acc[mt][nt], 0, 0, 0);
                acc[mt][nt] = __builtin_amdgcn_mfma_f32_16x16x32_bf16(ah.s, bl[nt].s, acc[mt][nt], 0, 0, 0);
            }
        }
    }
}

// bias + relu + C-layout -> next-stage A-frag layout (KC=4) for tile T
__device__ inline void epilogue_tile(const f32x4* acc, const float* __restrict__ bias,
                                     unsigned* __restrict__ Pout, int T, int lane) {
    int q = lane >> 4, ln = lane & 15;
    #pragma unroll
    for (int nt = 0; nt < 8; ++nt) {
        int col = nt * 16 + ln;
        float b = bias[col];
        int c = col >> 5, jj = col & 7, q2 = (col >> 3) & 3;
        int pb = ((T * 4 + c) * 8 + jj) * 66;
        #pragma unroll
        for (int r = 0; r < 4; ++r) {
            float v = fmaxf(acc[nt][r] + b, 0.f);
            Pout[pb + ((q * 4 + r) | (q2 << 4))] = bfpair(v);
        }
    }
}

// conv1 MLP: z16[M,64] -> relu(relu(z@Wa+ba)@Wb+bb) = h1 (fp16)
__global__ __launch_bounds__(256, 2) void mfma_mlp_A(const __half2* __restrict__ z16,
                                                     const short* __restrict__ WaH,
                                                     const short* __restrict__ WaL,
                                                     const float* __restrict__ ba,
                                                     const short* __restrict__ WbH,
                                                     const short* __restrict__ WbL,
                                                     const float* __restrict__ bb,
                                                     __half* __restrict__ H16out, int M) {
    __shared__ unsigned P[8 * 4 * 8 * 66];   // 67584 B
    const int t = threadIdx.x;
    const int w = t >> 6, lane = t & 63;
    const int m0 = blockIdx.x * 128;
    const int q = lane >> 4, ln = lane & 15;

    stage_global16<64>(z16, M, m0, P, t);
    __syncthreads();

    f32x4 acc[2][8];
    #pragma unroll
    for (int mt = 0; mt < 2; ++mt)
        #pragma unroll
        for (int i = 0; i < 8; ++i) acc[mt][i] = (f32x4){0.f, 0.f, 0.f, 0.f};
    stage_compute<64, 8>(P, WaH, WaL, w, lane, acc);
    __syncthreads();
    epilogue_tile(acc[0], ba, P, w * 2 + 0, lane);
    epilogue_tile(acc[1], ba, P, w * 2 + 1, lane);
    __syncthreads();

    #pragma unroll
    for (int mt = 0; mt < 2; ++mt)
        #pragma unroll
        for (int i = 0; i < 8; ++i) acc[mt][i] = (f32x4){0.f, 0.f, 0.f, 0.f};
    stage_compute<128, 8>(P, WbH, WbL, w, lane, acc);

    #pragma unroll
    for (int mt = 0; mt < 2; ++mt) {
        #pragma unroll
        for (int nt = 0; nt < 8; ++nt) {
            int col = nt * 16 + ln;
            float b = bb[col];
            #pragma unroll
            for (int r = 0; r < 4; ++r) {
                int row = m0 + (w * 2 + mt) * 16 + q * 4 + r;
                if (row < M) {
                    float v = fmaxf(acc[mt][nt][r] + b, 0.f);
                    H16out[(size_t)row * 128 + col] = __float2half_rn(v);
                }
            }
        }
    }
}

// conv2 MLP + head: z16[M,128] -> (relu(relu(z@Wa+ba)@Wb+bb))@Wl+bl = out[M,64]
__global__ __launch_bounds__(256, 2) void mfma_mlp_B(const __half2* __restrict__ z16,
                                                     const short* __restrict__ WaH,
                                                     const short* __restrict__ WaL,
                                                     const float* __restrict__ ba,
                                                     const short* __restrict__ WbH,
                                                     const short* __restrict__ WbL,
                                                     const float* __restrict__ bb,
                                                     const short* __restrict__ WlH,
                                                     const short* __restrict__ WlL,
                                                     const float* __restrict__ bl,
                                                     float* __restrict__ Out, int M) {
    __shared__ unsigned P[8 * 4 * 8 * 66];   // 67584 B
    const int t = threadIdx.x;
    const int w = t >> 6, lane = t & 63;
    const int m0 = blockIdx.x * 128;
    const int q = lane >> 4, ln = lane & 15;

    stage_global16<128>(z16, M, m0, P, t);
    __syncthreads();

    f32x4 acc[2][8];
    #pragma unroll
    for (int mt = 0; mt < 2; ++mt)
        #pragma unroll
        for (int i = 0; i < 8; ++i) acc[mt][i] = (f32x4){0.f, 0.f, 0.f, 0.f};
    stage_compute<128, 8>(P, WaH, WaL, w, lane, acc);
    __syncthreads();
    epilogue_tile(acc[0], ba, P, w * 2 + 0, lane);
    epilogue_tile(acc[1], ba, P, w * 2 + 1, lane);
    __syncthreads();

    #pragma unroll
    for (int mt = 0; mt < 2; ++mt)
        #pragma unroll
        for (int i = 0; i < 8; ++i) acc[mt][i] = (f32x4){0.f, 0.f, 0.f, 0.f};
    stage_compute<128, 8>(P, WbH, WbL, w, lane, acc);
    __syncthreads();
    epilogue_tile(acc[0], bb, P, w * 2 + 0, lane);
    epilogue_tile(acc[1], bb, P, w * 2 + 1, lane);
    __syncthreads();

    #pragma unroll
    for (int mt = 0; mt < 2; ++mt)
        #pragma unroll
        for (int i = 0; i < 8; ++i) acc[mt][i] = (f32x4){0.f, 0.f, 0.f, 0.f};
    stage_compute<128, 4>(P, WlH, WlL, w, lane, acc);

    #pragma unroll
    for (int mt = 0; mt < 2; ++mt) {
        #pragma unroll
        for (int nt = 0; nt < 4; ++nt) {
            int col = nt * 16 + ln;
            float b = bl[col];
            #pragma unroll
            for (int r = 0; r < 4; ++r) {
                int row = m0 + (w * 2 + mt) * 16 + q * 4 + r;
                if (row < M) Out[(size_t)row * 64 + col] = acc[mt][nt][r] + b;
            }
        }
    }
}

// ---------------------------------------------------------------------------

extern "C" void kernel_launch(void* const* d_in, const int* in_sizes, int n_in,
                              void* d_out, int out_size, void* d_ws, size_t ws_size,
                              hipStream_t stream) {
    const float* x    = (const float*)d_in[0];
    const int*   ei   = (const int*)d_in[1];
    const float* W1a  = (const float*)d_in[2];
    const float* b1a  = (const float*)d_in[3];
    const float* W1b  = (const float*)d_in[4];
    const float* b1b  = (const float*)d_in[5];
    const float* W2a  = (const float*)d_in[6];
    const float* b2a  = (const float*)d_in[7];
    const float* W2b  = (const float*)d_in[8];
    const float* b2b  = (const float*)d_in[9];
    const float* Wlin = (const float*)d_in[10];
    const float* blin = (const float*)d_in[11];
    float* out = (float*)d_out;

    const int N = in_sizes[0] / 64;   // 100000
    const int E = in_sizes[1] / 2;    // 1600000
    const int NBUCK = (N + BUCKET_NODES - 1) >> BUCKET_SHIFT;  // 196

    // workspace layout
    char* ws = (char*)d_ws;
    const size_t bufBytes = (size_t)N * 128 * sizeof(float);  // 51.2 MB
    __half2* Zbuf = (__half2*)(ws + 0);          // fp16 z (<=25.6 MB)
    char* B = ws + bufBytes;
    size_t off = 3 * bufBytes;
    int* row_start = (int*)(ws + off); off += ((size_t)(N + 1) * 4 + 15) & ~(size_t)15;
    int* cnt       = (int*)(ws + off); off += ((size_t)N * 4 + 15) & ~(size_t)15;
    int* partials  = (int*)(ws + off); off += 4096;
    int* gcur      = (int*)(ws + off); off += 4096;
    int* edge_src  = (int*)(ws + off); off += (size_t)E * 4;
    __half* h116   = (__half*)(ws + off); off += (size_t)N * 128 * 2;  // 25.6 MB
    // B-buffer interior aliases:
    int* gpk = (int*)B;                              // [0 .. 8MB)
    short* wHi = (short*)(B + (32u << 20));
    short* wLo = wHi + 65536;
    __half* x16 = (__half*)(B + (36u << 20));
    short* w1aH = wHi + 0;     short* w1aL = wLo + 0;
    short* w1bH = wHi + 8192;  short* w1bL = wLo + 8192;
    short* w2aH = wHi + 24576; short* w2aL = wLo + 24576;
    short* w2bH = wHi + 40960; short* w2bL = wLo + 40960;
    short* wlH  = wHi + 57344; short* wlL  = wLo + 57344;

    const int NB_N = (N + 255) / 256;          // 391
    const int NB_G = (N + 127) / 128;          // 782 MLP blocks
    const int NB_S = (E + EPB - 1) / EPB;      // 391 scatter blocks
    const int NB_A128 = (N + 3) / 4;           // 25000
    const int NB_A64  = (N + 7) / 8;           // 12500
    const int NB_CVT  = (N * 64 / 2 + 255) / 256;  // 12500

    // 0. weight prep + x fp16 shadow (independent of CSR chain)
    prep_weights_kernel<<<256, 256, 0, stream>>>(W1a, W1b, W2a, W2b, Wlin, wHi, wLo);
    convert_fp16_kernel<<<NB_CVT, 256, 0, stream>>>(x, (__half2*)x16, N * 32);

    // 1. CSR build, bucket-binned, packed staging
    init_gcur_kernel<<<1, 256, 0, stream>>>(gcur, NBUCK);
    bucket_scatter_kernel<<<NB_S, 256, 0, stream>>>(ei, E, gcur, gpk, NBUCK);
    bucket_hist_kernel<<<NBUCK, 256, 0, stream>>>(gpk, gcur, cnt, N);
    scan_block_kernel<<<NB_N, 256, 0, stream>>>(cnt, row_start, partials, N);
    scan_partials_kernel<<<1, 512, 0, stream>>>(partials, NB_N);
    scan_add_kernel<<<NB_N, 256, 0, stream>>>(row_start, partials, N, E);
    bucket_fill_kernel<<<NBUCK, 256, 0, stream>>>(gpk, gcur, row_start, edge_src, N);

    // 2. conv1: fp16 agg (fp16 out) + MFMA MLP (fp16 in/out)
    agg64_fp16<<<NB_A64, 256, 0, stream>>>((const __half2*)x16, row_start, edge_src, Zbuf, N);
    mfma_mlp_A<<<NB_G, 256, 0, stream>>>(Zbuf, w1aH, w1aL, b1a, w1bH, w1bL, b1b, h116, N);

    // 3. conv2 + head
    agg128_fp16<<<NB_A128, 256, 0, stream>>>((const __half2*)h116, row_start, edge_src, Zbuf, N);
    mfma_mlp_B<<<NB_G, 256, 0, stream>>>(Zbuf, w2aH, w2aL, b2a, w2bH, w2bL, b2b,
                                         wlH, wlL, blin, out, N);
}